// Round 2
// baseline (672.990 us; speedup 1.0000x reference)
//
#include <hip/hip_runtime.h>
#include <stdint.h>

#define DEV __device__ __forceinline__

typedef short s8v __attribute__((ext_vector_type(8)));      // 8 x bf16 (as i16 payload)
typedef float f4v __attribute__((ext_vector_type(4)));      // MFMA accumulator
typedef unsigned short u16;
typedef unsigned short u16x4 __attribute__((ext_vector_type(4)));

static constexpr float LAMBDA_INIT = 0.783605766531624464f;
static constexpr float OUT_SCALE   = 0.216394233468375536f;  // 1 - LAMBDA_INIT

DEV u16 f2bf(float f) {
    uint32_t u = __builtin_bit_cast(uint32_t, f);
    u += 0x7fffu + ((u >> 16) & 1u);          // round-to-nearest-even
    return (u16)(u >> 16);
}

// ---------------- GEMM: C[M,N] = A[M,K] @ B[N,K]^T + bias ----------------
// A_BF16: 0 = A is f32 (convert during staging), 1 = A is bf16
// OUT_MODE: 0 = bf16 row-major [M,N]; 1 = bf16 transposed [B][N][2048] (m = b*2048+s);
//           2 = f32 row-major [M,N]
template<int A_BF16, int OUT_MODE>
__global__ __launch_bounds__(256)
void gemm64(const void* __restrict__ Ap, const float* __restrict__ Bw,
            const float* __restrict__ bias, void* __restrict__ Cp,
            int M, int N, int K)
{
    __shared__ short As[64][72];   // +8 pad: 144B row stride -> ~2-way banks
    __shared__ short Bs[64][72];
    const int m0 = blockIdx.x * 64, n0 = blockIdx.y * 64;
    const int t = threadIdx.x, lane = t & 63, wave = t >> 6;
    const int wm = wave >> 1, wn = wave & 1, l15 = lane & 15, g = lane >> 4;

    f4v acc[2][2] = {};

    for (int k0 = 0; k0 < K; k0 += 64) {
        if (A_BF16) {
            const u16* A = (const u16*)Ap;
#pragma unroll
            for (int i = 0; i < 2; ++i) {
                int idx = t + i * 256, r = idx >> 3, c = (idx & 7) * 8;
                *(s8v*)&As[r][c] = *(const s8v*)(A + (size_t)(m0 + r) * K + k0 + c);
            }
        } else {
            const float* A = (const float*)Ap;
#pragma unroll
            for (int i = 0; i < 4; ++i) {
                int idx = t + i * 256, r = idx >> 4, c = (idx & 15) * 4;
                float4 va = *(const float4*)(A + (size_t)(m0 + r) * K + k0 + c);
                u16x4 pk = { f2bf(va.x), f2bf(va.y), f2bf(va.z), f2bf(va.w) };
                *(u16x4*)&As[r][c] = pk;
            }
        }
#pragma unroll
        for (int i = 0; i < 4; ++i) {
            int idx = t + i * 256, r = idx >> 4, c = (idx & 15) * 4;
            float4 vb = *(const float4*)(Bw + (size_t)(n0 + r) * K + k0 + c);
            u16x4 pk = { f2bf(vb.x), f2bf(vb.y), f2bf(vb.z), f2bf(vb.w) };
            *(u16x4*)&Bs[r][c] = pk;
        }
        __syncthreads();
#pragma unroll
        for (int ks = 0; ks < 2; ++ks) {
            s8v af[2], bf[2];
#pragma unroll
            for (int mt = 0; mt < 2; ++mt) af[mt] = *(const s8v*)&As[wm * 32 + mt * 16 + l15][ks * 32 + g * 8];
#pragma unroll
            for (int nt = 0; nt < 2; ++nt) bf[nt] = *(const s8v*)&Bs[wn * 32 + nt * 16 + l15][ks * 32 + g * 8];
#pragma unroll
            for (int mt = 0; mt < 2; ++mt)
#pragma unroll
                for (int nt = 0; nt < 2; ++nt)
                    acc[mt][nt] = __builtin_amdgcn_mfma_f32_16x16x32_bf16(af[mt], bf[nt], acc[mt][nt], 0, 0, 0);
        }
        __syncthreads();
    }

    float bv[2];
#pragma unroll
    for (int nt = 0; nt < 2; ++nt) bv[nt] = bias[n0 + wn * 32 + nt * 16 + l15];

#pragma unroll
    for (int mt = 0; mt < 2; ++mt)
#pragma unroll
        for (int nt = 0; nt < 2; ++nt)
#pragma unroll
            for (int r = 0; r < 4; ++r) {
                int m = m0 + wm * 32 + mt * 16 + g * 4 + r;
                int n = n0 + wn * 32 + nt * 16 + l15;
                float v = acc[mt][nt][r] + bv[nt];
                if (OUT_MODE == 0) {
                    ((u16*)Cp)[(size_t)m * N + n] = f2bf(v);
                } else if (OUT_MODE == 1) {
                    // transposed: [b][n][s], s = m & 2047, b = m >> 11
                    ((u16*)Cp)[((size_t)(m >> 11) * N + n) * 2048 + (m & 2047)] = f2bf(v);
                } else {
                    ((float*)Cp)[(size_t)m * N + n] = v;
                }
            }
}

// ---------------- lambda = exp(sum q1*k1) - exp(sum q2*k2) + LAMBDA_INIT --------------
__global__ void lam_kernel(const float* lq1, const float* lk1,
                           const float* lq2, const float* lk2, float* out)
{
    int t = threadIdx.x;  // 64
    float p1 = lq1[t] * lk1[t], p2 = lq2[t] * lk2[t];
#pragma unroll
    for (int off = 1; off < 64; off <<= 1) {
        p1 += __shfl_xor(p1, off);
        p2 += __shfl_xor(p2, off);
    }
    if (t == 0) out[0] = expf(p1) - expf(p2) + LAMBDA_INIT;
}

// ---------------- differential attention ----------------
// grid: 512 blocks = b(2) x h(8) x qtile(32); 256 threads = 4 waves x 16 q-rows
__global__ __launch_bounds__(256)
void attn_kernel(const u16* __restrict__ Qb, const u16* __restrict__ Kb,
                 const u16* __restrict__ Vt, const float* __restrict__ lamp,
                 const float* __restrict__ subw, float* __restrict__ aw,
                 u16* __restrict__ an)
{
    constexpr int S = 2048, D = 1024;
    const int bid = blockIdx.x;
    const int qt = bid & 31, h = (bid >> 5) & 7, b = bid >> 8;
    const int t = threadIdx.x, lane = t & 63, wave = t >> 6;
    const int l15 = lane & 15, g = lane >> 4;
    const int qrow0 = qt * 64 + wave * 16;
    const float lam = lamp[0];

    __shared__ short P[4][16][72];    // per-wave P strip (bf16)
    __shared__ short Vl[128][72];     // V^T tile: [d 128][kv 64] (+pad)

    // Q fragments in registers (16 rows per wave, two sub-heads)
    const u16* Qbase = Qb + ((size_t)b * S + qrow0 + l15) * D + h * 128;
    s8v q1[2], q2[2];
#pragma unroll
    for (int ks = 0; ks < 2; ++ks) {
        q1[ks] = *(const s8v*)(Qbase + ks * 32 + g * 8);
        q2[ks] = *(const s8v*)(Qbase + 64 + ks * 32 + g * 8);
    }
    const u16* Kbase = Kb + (size_t)b * S * D + h * 128;

    float m1[4], l1[4], m2[4], l2[4];
#pragma unroll
    for (int r = 0; r < 4; ++r) { m1[r] = -1e30f; l1[r] = 0.f; m2[r] = -1e30f; l2[r] = 0.f; }

    // ---- pass 1: softmax stats (online, no score storage) ----
    for (int kt = 0; kt < 32; ++kt) {
        const int kv0 = kt * 64;
        f4v s1[4] = {}; f4v s2[4] = {};
#pragma unroll
        for (int nt = 0; nt < 4; ++nt)
#pragma unroll
            for (int ks = 0; ks < 2; ++ks) {
                const u16* kp = Kbase + (size_t)(kv0 + nt * 16 + l15) * D + ks * 32 + g * 8;
                s1[nt] = __builtin_amdgcn_mfma_f32_16x16x32_bf16(q1[ks], *(const s8v*)kp, s1[nt], 0, 0, 0);
                s2[nt] = __builtin_amdgcn_mfma_f32_16x16x32_bf16(q2[ks], *(const s8v*)(kp + 64), s2[nt], 0, 0, 0);
            }
#pragma unroll
        for (int r = 0; r < 4; ++r) {
            float a0 = fmaxf(fmaxf(s1[0][r], s1[1][r]), fmaxf(s1[2][r], s1[3][r])) * 0.125f;
            float a1 = fmaxf(fmaxf(s2[0][r], s2[1][r]), fmaxf(s2[2][r], s2[3][r])) * 0.125f;
#pragma unroll
            for (int off = 1; off < 16; off <<= 1) {
                a0 = fmaxf(a0, __shfl_xor(a0, off));
                a1 = fmaxf(a1, __shfl_xor(a1, off));
            }
            float n1 = fmaxf(m1[r], a0), n2 = fmaxf(m2[r], a1);
            float t1 = 0.f, t2 = 0.f;
#pragma unroll
            for (int nt = 0; nt < 4; ++nt) {
                t1 += __expf(s1[nt][r] * 0.125f - n1);
                t2 += __expf(s2[nt][r] * 0.125f - n2);
            }
#pragma unroll
            for (int off = 1; off < 16; off <<= 1) {
                t1 += __shfl_xor(t1, off);
                t2 += __shfl_xor(t2, off);
            }
            l1[r] = l1[r] * __expf(m1[r] - n1) + t1; m1[r] = n1;
            l2[r] = l2[r] * __expf(m2[r] - n2) + t2; m2[r] = n2;
        }
    }
    float il1[4], il2[4];
#pragma unroll
    for (int r = 0; r < 4; ++r) { il1[r] = 1.f / l1[r]; il2[r] = 1.f / l2[r]; }

    f4v po[8] = {};  // PV accumulator: 16 q-rows x 128 d
    float* awb = aw + ((size_t)(b * 8 + h) * S + qrow0) * S;

    // ---- pass 2: recompute scores, write aw, accumulate PV ----
    for (int kt = 0; kt < 32; ++kt) {
        const int kv0 = kt * 64;
        __syncthreads();   // previous iteration's Vl readers done
#pragma unroll
        for (int i = 0; i < 4; ++i) {
            int idx = t + i * 256, dd = idx >> 3, c = (idx & 7) * 8;
            *(s8v*)&Vl[dd][c] = *(const s8v*)(Vt + ((size_t)b * 1024 + h * 128 + dd) * S + kv0 + c);
        }
        __syncthreads();   // Vl ready

        f4v s1[4] = {}; f4v s2[4] = {};
#pragma unroll
        for (int nt = 0; nt < 4; ++nt)
#pragma unroll
            for (int ks = 0; ks < 2; ++ks) {
                const u16* kp = Kbase + (size_t)(kv0 + nt * 16 + l15) * D + ks * 32 + g * 8;
                s1[nt] = __builtin_amdgcn_mfma_f32_16x16x32_bf16(q1[ks], *(const s8v*)kp, s1[nt], 0, 0, 0);
                s2[nt] = __builtin_amdgcn_mfma_f32_16x16x32_bf16(q2[ks], *(const s8v*)(kp + 64), s2[nt], 0, 0, 0);
            }
#pragma unroll
        for (int nt = 0; nt < 4; ++nt)
#pragma unroll
            for (int r = 0; r < 4; ++r) {
                float p1 = __expf(s1[nt][r] * 0.125f - m1[r]) * il1[r];
                float p2 = __expf(s2[nt][r] * 0.125f - m2[r]) * il2[r];
                float v = p1 - lam * p2;
                awb[(size_t)(g * 4 + r) * S + kv0 + nt * 16 + l15] = v;
                P[wave][g * 4 + r][nt * 16 + l15] = (short)f2bf(v);
            }
        __syncthreads();   // P strips written (also compiler ordering fence)

#pragma unroll
        for (int ks = 0; ks < 2; ++ks) {
            s8v pf = *(const s8v*)&P[wave][l15][ks * 32 + g * 8];
#pragma unroll
            for (int dn = 0; dn < 8; ++dn) {
                s8v vf = *(const s8v*)&Vl[dn * 16 + l15][ks * 32 + g * 8];
                po[dn] = __builtin_amdgcn_mfma_f32_16x16x32_bf16(pf, vf, po[dn], 0, 0, 0);
            }
        }
    }

    // ---- epilogue: RMS-norm over 128, * subln_w * (1-lambda_init) ----
    float sw[8];
#pragma unroll
    for (int dn = 0; dn < 8; ++dn) sw[dn] = subw[dn * 16 + l15];
#pragma unroll
    for (int r = 0; r < 4; ++r) {
        float ss = 0.f;
#pragma unroll
        for (int dn = 0; dn < 8; ++dn) ss += po[dn][r] * po[dn][r];
#pragma unroll
        for (int off = 1; off < 16; off <<= 1) ss += __shfl_xor(ss, off);
        float rs = rsqrtf(ss * (1.0f / 128.0f) + 1e-5f) * OUT_SCALE;
        u16* dst = an + ((size_t)b * S + qrow0 + g * 4 + r) * D + h * 128;
#pragma unroll
        for (int dn = 0; dn < 8; ++dn)
            dst[dn * 16 + l15] = f2bf(po[dn][r] * rs * sw[dn]);
    }
}

extern "C" void kernel_launch(void* const* d_in, const int* in_sizes, int n_in,
                              void* d_out, int out_size, void* d_ws, size_t ws_size,
                              hipStream_t stream)
{
    const float* query = (const float*)d_in[0];
    const float* key   = (const float*)d_in[1];
    const float* value = (const float*)d_in[2];
    const float* wq_w  = (const float*)d_in[3];
    const float* wq_b  = (const float*)d_in[4];
    const float* wk_w  = (const float*)d_in[5];
    const float* wk_b  = (const float*)d_in[6];
    const float* wv_w  = (const float*)d_in[7];
    const float* wv_b  = (const float*)d_in[8];
    const float* fc_w  = (const float*)d_in[9];
    const float* fc_b  = (const float*)d_in[10];
    const float* lq1   = (const float*)d_in[11];
    const float* lk1   = (const float*)d_in[12];
    const float* lq2   = (const float*)d_in[13];
    const float* lk2   = (const float*)d_in[14];
    const float* subw  = (const float*)d_in[15];

    char* ws = (char*)d_ws;
    u16*   Qbf = (u16*)(ws);                      // [2][2048][1024] bf16 = 8 MB
    u16*   Kbf = (u16*)(ws + (size_t)8  * 1024 * 1024);
    u16*   Vtg = (u16*)(ws + (size_t)16 * 1024 * 1024);  // [2][1024][2048] bf16
    u16*   ANb = (u16*)(ws + (size_t)24 * 1024 * 1024);  // [4096][1024] bf16
    float* lamp = (float*)(ws + (size_t)32 * 1024 * 1024);

    float* out0 = (float*)d_out;
    float* awp  = out0 + (size_t)4096 * 1024;

    dim3 grid(64, 16), blk(256);
    gemm64<0, 0><<<grid, blk, 0, stream>>>(query, wq_w, wq_b, Qbf, 4096, 1024, 1024);
    gemm64<0, 0><<<grid, blk, 0, stream>>>(key,   wk_w, wk_b, Kbf, 4096, 1024, 1024);
    gemm64<0, 1><<<grid, blk, 0, stream>>>(value, wv_w, wv_b, Vtg, 4096, 1024, 1024);
    lam_kernel<<<dim3(1), dim3(64), 0, stream>>>(lq1, lk1, lq2, lk2, lamp);
    attn_kernel<<<dim3(512), blk, 0, stream>>>(Qbf, Kbf, Vtg, lamp, subw, awp, ANb);
    gemm64<1, 2><<<grid, blk, 0, stream>>>(ANb, fc_w, fc_b, out0, 4096, 1024, 1024);
}

// Round 3
// 627.770 us; speedup vs baseline: 1.0720x; 1.0720x over previous
//
#include <hip/hip_runtime.h>
#include <stdint.h>

#define DEV __device__ __forceinline__

typedef short s8v __attribute__((ext_vector_type(8)));      // 8 x bf16 (as i16 payload)
typedef float f4v __attribute__((ext_vector_type(4)));      // MFMA accumulator
typedef unsigned short u16;
typedef unsigned short u16x4 __attribute__((ext_vector_type(4)));

static constexpr float LAMBDA_INIT = 0.783605766531624464f;
static constexpr float OUT_SCALE   = 0.216394233468375536f;  // 1 - LAMBDA_INIT

DEV u16 f2bf(float f) {
    uint32_t u = __builtin_bit_cast(uint32_t, f);
    u += 0x7fffu + ((u >> 16) & 1u);          // round-to-nearest-even
    return (u16)(u >> 16);
}

// ---------------- GEMM: C[M,N] = A[M,K] @ B[N,K]^T + bias ----------------
// A_BF16: 0 = A is f32 (convert during staging), 1 = A is bf16
// OUT_MODE: 0 = bf16 row-major [M,N]; 1 = bf16 transposed [B][N][2048] (m = b*2048+s);
//           2 = f32 row-major [M,N]
template<int A_BF16, int OUT_MODE>
__global__ __launch_bounds__(256)
void gemm64(const void* __restrict__ Ap, const float* __restrict__ Bw,
            const float* __restrict__ bias, void* __restrict__ Cp,
            int M, int N, int K)
{
    __shared__ short As[64][72];   // +8 pad: 144B row stride -> ~2-way banks
    __shared__ short Bs[64][72];
    const int m0 = blockIdx.x * 64, n0 = blockIdx.y * 64;
    const int t = threadIdx.x, lane = t & 63, wave = t >> 6;
    const int wm = wave >> 1, wn = wave & 1, l15 = lane & 15, g = lane >> 4;

    f4v acc[2][2] = {};

    for (int k0 = 0; k0 < K; k0 += 64) {
        if (A_BF16) {
            const u16* A = (const u16*)Ap;
#pragma unroll
            for (int i = 0; i < 2; ++i) {
                int idx = t + i * 256, r = idx >> 3, c = (idx & 7) * 8;
                *(s8v*)&As[r][c] = *(const s8v*)(A + (size_t)(m0 + r) * K + k0 + c);
            }
        } else {
            const float* A = (const float*)Ap;
#pragma unroll
            for (int i = 0; i < 4; ++i) {
                int idx = t + i * 256, r = idx >> 4, c = (idx & 15) * 4;
                float4 va = *(const float4*)(A + (size_t)(m0 + r) * K + k0 + c);
                u16x4 pk = { f2bf(va.x), f2bf(va.y), f2bf(va.z), f2bf(va.w) };
                *(u16x4*)&As[r][c] = pk;
            }
        }
#pragma unroll
        for (int i = 0; i < 4; ++i) {
            int idx = t + i * 256, r = idx >> 4, c = (idx & 15) * 4;
            float4 vb = *(const float4*)(Bw + (size_t)(n0 + r) * K + k0 + c);
            u16x4 pk = { f2bf(vb.x), f2bf(vb.y), f2bf(vb.z), f2bf(vb.w) };
            *(u16x4*)&Bs[r][c] = pk;
        }
        __syncthreads();
#pragma unroll
        for (int ks = 0; ks < 2; ++ks) {
            s8v af[2], bf[2];
#pragma unroll
            for (int mt = 0; mt < 2; ++mt) af[mt] = *(const s8v*)&As[wm * 32 + mt * 16 + l15][ks * 32 + g * 8];
#pragma unroll
            for (int nt = 0; nt < 2; ++nt) bf[nt] = *(const s8v*)&Bs[wn * 32 + nt * 16 + l15][ks * 32 + g * 8];
#pragma unroll
            for (int mt = 0; mt < 2; ++mt)
#pragma unroll
                for (int nt = 0; nt < 2; ++nt)
                    acc[mt][nt] = __builtin_amdgcn_mfma_f32_16x16x32_bf16(af[mt], bf[nt], acc[mt][nt], 0, 0, 0);
        }
        __syncthreads();
    }

    float bv[2];
#pragma unroll
    for (int nt = 0; nt < 2; ++nt) bv[nt] = bias[n0 + wn * 32 + nt * 16 + l15];

#pragma unroll
    for (int mt = 0; mt < 2; ++mt)
#pragma unroll
        for (int nt = 0; nt < 2; ++nt)
#pragma unroll
            for (int r = 0; r < 4; ++r) {
                int m = m0 + wm * 32 + mt * 16 + g * 4 + r;
                int n = n0 + wn * 32 + nt * 16 + l15;
                float v = acc[mt][nt][r] + bv[nt];
                if (OUT_MODE == 0) {
                    ((u16*)Cp)[(size_t)m * N + n] = f2bf(v);
                } else if (OUT_MODE == 1) {
                    // transposed: [b][n][s], s = m & 2047, b = m >> 11
                    ((u16*)Cp)[((size_t)(m >> 11) * N + n) * 2048 + (m & 2047)] = f2bf(v);
                } else {
                    ((float*)Cp)[(size_t)m * N + n] = v;
                }
            }
}

// ---------------- lambda = exp(sum q1*k1) - exp(sum q2*k2) + LAMBDA_INIT --------------
__global__ void lam_kernel(const float* lq1, const float* lk1,
                           const float* lq2, const float* lk2, float* out)
{
    int t = threadIdx.x;  // 64
    float p1 = lq1[t] * lk1[t], p2 = lq2[t] * lk2[t];
#pragma unroll
    for (int off = 1; off < 64; off <<= 1) {
        p1 += __shfl_xor(p1, off);
        p2 += __shfl_xor(p2, off);
    }
    if (t == 0) out[0] = expf(p1) - expf(p2) + LAMBDA_INIT;
}

// ---------------- differential attention ----------------
// grid: 2048 blocks = b(2) x h(8) x qtile(128); 256 threads = 4 waves.
// Each block owns 16 q-rows; wave w owns kv range [w*512, (w+1)*512).
__global__ __launch_bounds__(256)
void attn_kernel(const u16* __restrict__ Qb, const u16* __restrict__ Kb,
                 const u16* __restrict__ Vt, const float* __restrict__ lamp,
                 const float* __restrict__ subw, float* __restrict__ aw,
                 u16* __restrict__ an)
{
    constexpr int S = 2048, D = 1024;
    const int bid = blockIdx.x;
    const int qt = bid & 127, h = (bid >> 7) & 7, b = bid >> 10;
    const int t = threadIdx.x, lane = t & 63, wave = t >> 6;
    const int l15 = lane & 15, g = lane >> 4;
    const int qrow0 = qt * 16;
    const float lam = lamp[0];

    __shared__ short P[4][16][72];    // per-wave P strip (bf16)
    __shared__ float Po[16][132];     // cross-wave PV reduction
    __shared__ float sst[4][4][16];   // [wave][{m1,l1,m2,l2}][row]

    // Q fragments in registers (16 rows, two sub-heads) — same for all waves
    const u16* Qbase = Qb + ((size_t)b * S + qrow0 + l15) * D + h * 128;
    s8v q1[2], q2[2];
#pragma unroll
    for (int ks = 0; ks < 2; ++ks) {
        q1[ks] = *(const s8v*)(Qbase + ks * 32 + g * 8);
        q2[ks] = *(const s8v*)(Qbase + 64 + ks * 32 + g * 8);
    }
    const u16* Kbase = Kb + (size_t)b * S * D + h * 128;
    const u16* Vbase = Vt + ((size_t)b * 1024 + h * 128) * 2048;  // [d][s]

    float m1[4], l1[4], m2[4], l2[4];
#pragma unroll
    for (int r = 0; r < 4; ++r) { m1[r] = -1e30f; l1[r] = 0.f; m2[r] = -1e30f; l2[r] = 0.f; }

    // ---- pass 1: per-wave softmax stats over its kv slice ----
    for (int kt = wave * 8; kt < wave * 8 + 8; ++kt) {
        const int kv0 = kt * 64;
        f4v s1[4] = {}; f4v s2[4] = {};
#pragma unroll
        for (int nt = 0; nt < 4; ++nt)
#pragma unroll
            for (int ks = 0; ks < 2; ++ks) {
                const u16* kp = Kbase + (size_t)(kv0 + nt * 16 + l15) * D + ks * 32 + g * 8;
                s1[nt] = __builtin_amdgcn_mfma_f32_16x16x32_bf16(q1[ks], *(const s8v*)kp, s1[nt], 0, 0, 0);
                s2[nt] = __builtin_amdgcn_mfma_f32_16x16x32_bf16(q2[ks], *(const s8v*)(kp + 64), s2[nt], 0, 0, 0);
            }
#pragma unroll
        for (int r = 0; r < 4; ++r) {
            float a0 = fmaxf(fmaxf(s1[0][r], s1[1][r]), fmaxf(s1[2][r], s1[3][r])) * 0.125f;
            float a1 = fmaxf(fmaxf(s2[0][r], s2[1][r]), fmaxf(s2[2][r], s2[3][r])) * 0.125f;
#pragma unroll
            for (int off = 1; off < 16; off <<= 1) {
                a0 = fmaxf(a0, __shfl_xor(a0, off));
                a1 = fmaxf(a1, __shfl_xor(a1, off));
            }
            float n1 = fmaxf(m1[r], a0), n2 = fmaxf(m2[r], a1);
            float t1 = 0.f, t2 = 0.f;
#pragma unroll
            for (int nt = 0; nt < 4; ++nt) {
                t1 += __expf(s1[nt][r] * 0.125f - n1);
                t2 += __expf(s2[nt][r] * 0.125f - n2);
            }
#pragma unroll
            for (int off = 1; off < 16; off <<= 1) {
                t1 += __shfl_xor(t1, off);
                t2 += __shfl_xor(t2, off);
            }
            l1[r] = l1[r] * __expf(m1[r] - n1) + t1; m1[r] = n1;
            l2[r] = l2[r] * __expf(m2[r] - n2) + t2; m2[r] = n2;
        }
    }

    // ---- cross-wave stat combine ----
    if (l15 == 0) {
#pragma unroll
        for (int r = 0; r < 4; ++r) {
            int row = g * 4 + r;
            sst[wave][0][row] = m1[r]; sst[wave][1][row] = l1[r];
            sst[wave][2][row] = m2[r]; sst[wave][3][row] = l2[r];
        }
    }
    __syncthreads();
    float il1[4], il2[4];
#pragma unroll
    for (int r = 0; r < 4; ++r) {
        int row = g * 4 + r;
        float M1 = -1e30f, M2 = -1e30f;
#pragma unroll
        for (int w = 0; w < 4; ++w) {
            M1 = fmaxf(M1, sst[w][0][row]);
            M2 = fmaxf(M2, sst[w][2][row]);
        }
        float L1 = 0.f, L2 = 0.f;
#pragma unroll
        for (int w = 0; w < 4; ++w) {
            L1 += sst[w][1][row] * __expf(sst[w][0][row] - M1);
            L2 += sst[w][3][row] * __expf(sst[w][2][row] - M2);
        }
        m1[r] = M1; m2[r] = M2;
        il1[r] = 1.f / L1; il2[r] = 1.f / L2;
    }

    f4v po[8] = {};  // partial PV accumulator: 16 q-rows x 128 d (this wave's kv slice)
    float* awb = aw + ((size_t)(b * 8 + h) * S + qrow0) * S;

    // ---- pass 2: recompute scores, write aw, accumulate partial PV ----
    for (int kt = wave * 8; kt < wave * 8 + 8; ++kt) {
        const int kv0 = kt * 64;
        f4v s1[4] = {}; f4v s2[4] = {};
#pragma unroll
        for (int nt = 0; nt < 4; ++nt)
#pragma unroll
            for (int ks = 0; ks < 2; ++ks) {
                const u16* kp = Kbase + (size_t)(kv0 + nt * 16 + l15) * D + ks * 32 + g * 8;
                s1[nt] = __builtin_amdgcn_mfma_f32_16x16x32_bf16(q1[ks], *(const s8v*)kp, s1[nt], 0, 0, 0);
                s2[nt] = __builtin_amdgcn_mfma_f32_16x16x32_bf16(q2[ks], *(const s8v*)(kp + 64), s2[nt], 0, 0, 0);
            }
#pragma unroll
        for (int nt = 0; nt < 4; ++nt)
#pragma unroll
            for (int r = 0; r < 4; ++r) {
                float p1 = __expf(s1[nt][r] * 0.125f - m1[r]) * il1[r];
                float p2 = __expf(s2[nt][r] * 0.125f - m2[r]) * il2[r];
                float v = p1 - lam * p2;
                awb[(size_t)(g * 4 + r) * S + kv0 + nt * 16 + l15] = v;
                P[wave][g * 4 + r][nt * 16 + l15] = (short)f2bf(v);
            }
        __syncthreads();   // P strip visible (per-wave data; barrier also orders LDS)

#pragma unroll
        for (int ks = 0; ks < 2; ++ks) {
            s8v pf = *(const s8v*)&P[wave][l15][ks * 32 + g * 8];
#pragma unroll
            for (int dn = 0; dn < 8; ++dn) {
                s8v vf = *(const s8v*)(Vbase + (size_t)(dn * 16 + l15) * 2048 + kv0 + ks * 32 + g * 8);
                po[dn] = __builtin_amdgcn_mfma_f32_16x16x32_bf16(pf, vf, po[dn], 0, 0, 0);
            }
        }
        __syncthreads();   // P reads done before next iteration's writes
    }

    // ---- cross-wave PV reduction (serialized: deterministic) ----
#pragma unroll
    for (int w = 0; w < 4; ++w) {
        if (wave == w) {
#pragma unroll
            for (int dn = 0; dn < 8; ++dn)
#pragma unroll
                for (int r = 0; r < 4; ++r) {
                    if (w == 0) Po[g * 4 + r][dn * 16 + l15]  = po[dn][r];
                    else        Po[g * 4 + r][dn * 16 + l15] += po[dn][r];
                }
        }
        __syncthreads();
    }

    // ---- epilogue: RMS-norm over 128, * subln_w * (1-lambda_init) ----
    {
        const int row = t >> 4, c0 = t & 15;
        float pv[8], ss = 0.f;
#pragma unroll
        for (int j = 0; j < 8; ++j) {
            pv[j] = Po[row][c0 + 16 * j];
            ss += pv[j] * pv[j];
        }
#pragma unroll
        for (int off = 1; off < 16; off <<= 1) ss += __shfl_xor(ss, off);
        float rs = rsqrtf(ss * (1.0f / 128.0f) + 1e-5f) * OUT_SCALE;
        u16* dst = an + ((size_t)b * S + qrow0 + row) * D + h * 128;
#pragma unroll
        for (int j = 0; j < 8; ++j)
            dst[c0 + 16 * j] = f2bf(pv[j] * rs * subw[c0 + 16 * j]);
    }
}

extern "C" void kernel_launch(void* const* d_in, const int* in_sizes, int n_in,
                              void* d_out, int out_size, void* d_ws, size_t ws_size,
                              hipStream_t stream)
{
    const float* query = (const float*)d_in[0];
    const float* key   = (const float*)d_in[1];
    const float* value = (const float*)d_in[2];
    const float* wq_w  = (const float*)d_in[3];
    const float* wq_b  = (const float*)d_in[4];
    const float* wk_w  = (const float*)d_in[5];
    const float* wk_b  = (const float*)d_in[6];
    const float* wv_w  = (const float*)d_in[7];
    const float* wv_b  = (const float*)d_in[8];
    const float* fc_w  = (const float*)d_in[9];
    const float* fc_b  = (const float*)d_in[10];
    const float* lq1   = (const float*)d_in[11];
    const float* lk1   = (const float*)d_in[12];
    const float* lq2   = (const float*)d_in[13];
    const float* lk2   = (const float*)d_in[14];
    const float* subw  = (const float*)d_in[15];

    char* ws = (char*)d_ws;
    u16*   Qbf = (u16*)(ws);                      // [2][2048][1024] bf16 = 8 MB
    u16*   Kbf = (u16*)(ws + (size_t)8  * 1024 * 1024);
    u16*   Vtg = (u16*)(ws + (size_t)16 * 1024 * 1024);  // [2][1024][2048] bf16
    u16*   ANb = (u16*)(ws + (size_t)24 * 1024 * 1024);  // [4096][1024] bf16
    float* lamp = (float*)(ws + (size_t)32 * 1024 * 1024);

    float* out0 = (float*)d_out;
    float* awp  = out0 + (size_t)4096 * 1024;

    dim3 grid(64, 16), blk(256);
    gemm64<0, 0><<<grid, blk, 0, stream>>>(query, wq_w, wq_b, Qbf, 4096, 1024, 1024);
    gemm64<0, 0><<<grid, blk, 0, stream>>>(key,   wk_w, wk_b, Kbf, 4096, 1024, 1024);
    gemm64<0, 1><<<grid, blk, 0, stream>>>(value, wv_w, wv_b, Vtg, 4096, 1024, 1024);
    lam_kernel<<<dim3(1), dim3(64), 0, stream>>>(lq1, lk1, lq2, lk2, lamp);
    attn_kernel<<<dim3(2048), blk, 0, stream>>>(Qbf, Kbf, Vtg, lamp, subw, awp, ANb);
    gemm64<1, 2><<<grid, blk, 0, stream>>>(ANb, fc_w, fc_b, out0, 4096, 1024, 1024);
}

// Round 4
// 289.465 us; speedup vs baseline: 2.3249x; 2.1687x over previous
//
#include <hip/hip_runtime.h>
#include <stdint.h>

#define DEV __device__ __forceinline__

typedef short s8v __attribute__((ext_vector_type(8)));      // 8 x bf16 (as i16 payload)
typedef float f4v __attribute__((ext_vector_type(4)));      // MFMA accumulator
typedef unsigned short u16;

static constexpr float LAMBDA_INIT = 0.783605766531624464f;
static constexpr float OUT_SCALE   = 0.216394233468375536f;  // 1 - LAMBDA_INIT

DEV u16 f2bf(float f) {
    uint32_t u = __builtin_bit_cast(uint32_t, f);
    u += 0x7fffu + ((u >> 16) & 1u);          // round-to-nearest-even
    return (u16)(u >> 16);
}

// ---------------- f32 -> bf16 bulk convert (7 tensors, one launch) --------
__global__ __launch_bounds__(256)
void cvt_kernel(const float* __restrict__ q, const float* __restrict__ k,
                const float* __restrict__ v, const float* __restrict__ w0,
                const float* __restrict__ w1, const float* __restrict__ w2,
                const float* __restrict__ w3,
                u16* qo, u16* ko, u16* vo, u16* o0, u16* o1, u16* o2, u16* o3)
{
    int bid = blockIdx.x;
    const float* src; u16* dst; int base;
    if      (bid < 2048) { src = q;  dst = qo; base = bid * 2048; }
    else if (bid < 4096) { src = k;  dst = ko; base = (bid - 2048) * 2048; }
    else if (bid < 6144) { src = v;  dst = vo; base = (bid - 4096) * 2048; }
    else if (bid < 6656) { src = w0; dst = o0; base = (bid - 6144) * 2048; }
    else if (bid < 7168) { src = w1; dst = o1; base = (bid - 6656) * 2048; }
    else if (bid < 7680) { src = w2; dst = o2; base = (bid - 7168) * 2048; }
    else                 { src = w3; dst = o3; base = (bid - 7680) * 2048; }
    int i = base + threadIdx.x * 8;
    float4 a = *(const float4*)(src + i);
    float4 b = *(const float4*)(src + i + 4);
    u16 r[8] = { f2bf(a.x), f2bf(a.y), f2bf(a.z), f2bf(a.w),
                 f2bf(b.x), f2bf(b.y), f2bf(b.z), f2bf(b.w) };
    *(s8v*)(dst + i) = *(const s8v*)r;
}

// ---------------- GEMM: C[M,N-tile] = A[M,K]bf16 @ W[N,K]bf16^T + bias -----
// Tile 128x64, BK=64, 4 waves. Swizzled LDS staging (dense global reads),
// LDS-repack epilogues (dense global writes).
// OUT_MODE: 0 = bf16 row-major [M,1024]; 1 = bf16 transposed [b][n][2048]; 2 = f32 [M,1024]
template<int OUT_MODE>
__global__ __launch_bounds__(256)
void gemm128(const u16* __restrict__ A, const u16* __restrict__ W,
             const float* __restrict__ bias, void* __restrict__ Cp)
{
    constexpr int K = 1024;
    __shared__ __align__(16) char smem[OUT_MODE == 2 ? 32768 : 24576];
    // As @0: [128 rows][128B] swizzled; Bs @16384: [64 rows][128B] swizzled
    const int m0 = blockIdx.x * 128, n0 = blockIdx.y * 64;
    const int t = threadIdx.x, lane = t & 63, wave = t >> 6;
    const int l15 = lane & 15, g = lane >> 4;

    f4v acc[2][4] = {};

    for (int k0 = 0; k0 < K; k0 += 64) {
#pragma unroll
        for (int i = 0; i < 4; ++i) {            // A: 16KB
            int idx = t + i * 256, row = idx >> 3, piece = idx & 7;
            s8v v = *(const s8v*)(A + (size_t)(m0 + row) * K + k0 + piece * 8);
            *(s8v*)(smem + row * 128 + ((piece * 16) ^ ((row & 7) << 4))) = v;
        }
#pragma unroll
        for (int i = 0; i < 2; ++i) {            // B: 8KB
            int idx = t + i * 256, row = idx >> 3, piece = idx & 7;
            s8v v = *(const s8v*)(W + (size_t)(n0 + row) * K + k0 + piece * 8);
            *(s8v*)(smem + 16384 + row * 128 + ((piece * 16) ^ ((row & 7) << 4))) = v;
        }
        __syncthreads();
#pragma unroll
        for (int ks = 0; ks < 2; ++ks) {
            s8v af[2], bf4[4];
#pragma unroll
            for (int mt = 0; mt < 2; ++mt) {
                int row = wave * 32 + mt * 16 + l15;
                af[mt] = *(const s8v*)(smem + row * 128 + ((ks * 64 + g * 16) ^ ((l15 & 7) << 4)));
            }
#pragma unroll
            for (int nt = 0; nt < 4; ++nt) {
                int row = nt * 16 + l15;
                bf4[nt] = *(const s8v*)(smem + 16384 + row * 128 + ((ks * 64 + g * 16) ^ ((l15 & 7) << 4)));
            }
#pragma unroll
            for (int mt = 0; mt < 2; ++mt)
#pragma unroll
                for (int nt = 0; nt < 4; ++nt)
                    acc[mt][nt] = __builtin_amdgcn_mfma_f32_16x16x32_bf16(af[mt], bf4[nt], acc[mt][nt], 0, 0, 0);
        }
        __syncthreads();
    }

    float bv[4];
#pragma unroll
    for (int nt = 0; nt < 4; ++nt) bv[nt] = bias[n0 + nt * 16 + l15];

    // ---- repack epilogue (staging LDS is dead; barrier above guarantees) ----
    if (OUT_MODE == 0) {
        u16* rep = (u16*)smem;                    // [128][64]
#pragma unroll
        for (int mt = 0; mt < 2; ++mt)
#pragma unroll
            for (int nt = 0; nt < 4; ++nt)
#pragma unroll
                for (int r = 0; r < 4; ++r)
                    rep[(wave * 32 + mt * 16 + g * 4 + r) * 64 + nt * 16 + l15] = f2bf(acc[mt][nt][r] + bv[nt]);
        __syncthreads();
        u16* C = (u16*)Cp;
#pragma unroll
        for (int j = 0; j < 4; ++j) {
            int m = j * 32 + (t >> 3), chunk = t & 7;
            s8v v = *(const s8v*)(smem + m * 128 + chunk * 16);
            *(s8v*)(C + (size_t)(m0 + m) * 1024 + n0 + chunk * 8) = v;
        }
    } else if (OUT_MODE == 1) {
        u16* LT = (u16*)smem;                     // [64 n][136]
#pragma unroll
        for (int mt = 0; mt < 2; ++mt)
#pragma unroll
            for (int nt = 0; nt < 4; ++nt)
#pragma unroll
                for (int r = 0; r < 4; ++r)
                    LT[(nt * 16 + l15) * 136 + wave * 32 + mt * 16 + g * 4 + r] = f2bf(acc[mt][nt][r] + bv[nt]);
        __syncthreads();
        u16* C = (u16*)Cp;
        const int b = m0 >> 11, s0 = m0 & 2047;
#pragma unroll
        for (int j = 0; j < 4; ++j) {
            int n = j * 16 + (t >> 4), chunk = t & 15;
            s8v v = *(const s8v*)(smem + n * 272 + chunk * 16);
            *(s8v*)(C + ((size_t)b * 1024 + n0 + n) * 2048 + s0 + chunk * 8) = v;
        }
    } else {
        float* rep = (float*)smem;                // [128][64] f32 = 32KB
#pragma unroll
        for (int mt = 0; mt < 2; ++mt)
#pragma unroll
            for (int nt = 0; nt < 4; ++nt)
#pragma unroll
                for (int r = 0; r < 4; ++r)
                    rep[(wave * 32 + mt * 16 + g * 4 + r) * 64 + nt * 16 + l15] = acc[mt][nt][r] + bv[nt];
        __syncthreads();
        float* C = (float*)Cp;
#pragma unroll
        for (int j = 0; j < 8; ++j) {
            int m = j * 16 + (t >> 4), c4 = t & 15;
            float4 v = *(const float4*)(smem + m * 256 + c4 * 16);
            *(float4*)(C + (size_t)(m0 + m) * 1024 + n0 + c4 * 4) = v;
        }
    }
}

// ---------------- lambda scalar --------------------------------------------
__global__ void lam_kernel(const float* lq1, const float* lk1,
                           const float* lq2, const float* lk2, float* out)
{
    int t = threadIdx.x;  // 64
    float p1 = lq1[t] * lk1[t], p2 = lq2[t] * lk2[t];
#pragma unroll
    for (int off = 1; off < 64; off <<= 1) {
        p1 += __shfl_xor(p1, off);
        p2 += __shfl_xor(p2, off);
    }
    if (t == 0) out[0] = expf(p1) - expf(p2) + LAMBDA_INIT;
}

// ---------------- differential attention -----------------------------------
// 512 blocks = b(2) x h(8) x qtile(32); 4 waves x 16 q-rows; shared kv tiles.
__global__ __launch_bounds__(256)
void attn_kernel(const u16* __restrict__ Qb, const u16* __restrict__ Kb,
                 const u16* __restrict__ Vt, const float* __restrict__ lamp,
                 const float* __restrict__ subw, float* __restrict__ aw,
                 u16* __restrict__ an)
{
    constexpr int S = 2048, D = 1024;
    __shared__ __align__(16) char smem[59392];
    // Ks @0: [2 sub][64 kv][128B] swizzled (16KB)
    // Vs @16384: [128 d][128B kv] swizzled (16KB)
    // P  @32768: [4][16][72] u16 (9216B)
    // awS@41984: [64][68] f32 (17408B)
    const int bid = blockIdx.x;
    const int qt = bid & 31, h = (bid >> 5) & 7, b = bid >> 8;
    const int t = threadIdx.x, lane = t & 63, wave = t >> 6;
    const int l15 = lane & 15, g = lane >> 4;
    const int qrow0 = qt * 64, wrow0 = qrow0 + wave * 16;
    const float lam = lamp[0];

    short* Pw  = (short*)(smem + 32768) + wave * 16 * 72;
    float* awS = (float*)(smem + 41984);

    // Q fragments (registers)
    const u16* Qbase = Qb + ((size_t)b * S + wrow0 + l15) * D + h * 128;
    s8v q1[2], q2[2];
#pragma unroll
    for (int ks = 0; ks < 2; ++ks) {
        q1[ks] = *(const s8v*)(Qbase + ks * 32 + g * 8);
        q2[ks] = *(const s8v*)(Qbase + 64 + ks * 32 + g * 8);
    }
    const u16* Ksrc = Kb + (size_t)b * S * D + h * 128;
    const u16* Vsrc = Vt + ((size_t)b * 1024 + h * 128) * 2048;

    const int swz = (l15 & 7) << 4;

    float m1[4], l1[4], m2[4], l2[4];
#pragma unroll
    for (int r = 0; r < 4; ++r) { m1[r] = -1e30f; l1[r] = 0.f; m2[r] = -1e30f; l2[r] = 0.f; }

    // ---- pass 1: softmax stats (K staged in LDS) ----
    for (int kt = 0; kt < 32; ++kt) {
        const int kv0 = kt * 64;
        __syncthreads();
#pragma unroll
        for (int i = 0; i < 4; ++i) {          // K tile: 64 rows x 256B (both subheads)
            int idx = t + i * 256, row = idx >> 4, piece = idx & 15;
            s8v v = *(const s8v*)(Ksrc + (size_t)(kv0 + row) * D + piece * 8);
            int sub = piece >> 3, colB = (piece & 7) * 16;
            *(s8v*)(smem + sub * 8192 + row * 128 + (colB ^ ((row & 7) << 4))) = v;
        }
        __syncthreads();

        f4v s1[4] = {}; f4v s2[4] = {};
#pragma unroll
        for (int nt = 0; nt < 4; ++nt)
#pragma unroll
            for (int ks = 0; ks < 2; ++ks) {
                int ro = (nt * 16 + l15) * 128 + ((ks * 64 + g * 16) ^ swz);
                s1[nt] = __builtin_amdgcn_mfma_f32_16x16x32_bf16(q1[ks], *(const s8v*)(smem + ro), s1[nt], 0, 0, 0);
                s2[nt] = __builtin_amdgcn_mfma_f32_16x16x32_bf16(q2[ks], *(const s8v*)(smem + 8192 + ro), s2[nt], 0, 0, 0);
            }
#pragma unroll
        for (int r = 0; r < 4; ++r) {
            float a0 = fmaxf(fmaxf(s1[0][r], s1[1][r]), fmaxf(s1[2][r], s1[3][r])) * 0.125f;
            float a1 = fmaxf(fmaxf(s2[0][r], s2[1][r]), fmaxf(s2[2][r], s2[3][r])) * 0.125f;
#pragma unroll
            for (int off = 1; off < 16; off <<= 1) {
                a0 = fmaxf(a0, __shfl_xor(a0, off));
                a1 = fmaxf(a1, __shfl_xor(a1, off));
            }
            float n1 = fmaxf(m1[r], a0), n2 = fmaxf(m2[r], a1);
            float t1 = 0.f, t2 = 0.f;
#pragma unroll
            for (int nt = 0; nt < 4; ++nt) {
                t1 += __expf(s1[nt][r] * 0.125f - n1);
                t2 += __expf(s2[nt][r] * 0.125f - n2);
            }
#pragma unroll
            for (int off = 1; off < 16; off <<= 1) {
                t1 += __shfl_xor(t1, off);
                t2 += __shfl_xor(t2, off);
            }
            l1[r] = l1[r] * __expf(m1[r] - n1) + t1; m1[r] = n1;
            l2[r] = l2[r] * __expf(m2[r] - n2) + t2; m2[r] = n2;
        }
    }
    float il1[4], il2[4];
#pragma unroll
    for (int r = 0; r < 4; ++r) { il1[r] = 1.f / l1[r]; il2[r] = 1.f / l2[r]; }

    f4v po[8] = {};
    float* awb = aw + ((size_t)(b * 8 + h) * S + qrow0) * S;

    // ---- pass 2: scores, aw (via LDS), PV ----
    for (int kt = 0; kt < 32; ++kt) {
        const int kv0 = kt * 64;
        __syncthreads();
#pragma unroll
        for (int i = 0; i < 4; ++i) {          // K tile
            int idx = t + i * 256, row = idx >> 4, piece = idx & 15;
            s8v v = *(const s8v*)(Ksrc + (size_t)(kv0 + row) * D + piece * 8);
            int sub = piece >> 3, colB = (piece & 7) * 16;
            *(s8v*)(smem + sub * 8192 + row * 128 + (colB ^ ((row & 7) << 4))) = v;
        }
#pragma unroll
        for (int i = 0; i < 4; ++i) {          // V tile: 128 d-rows x 128B
            int idx = t + i * 256, dd = idx >> 3, piece = idx & 7;
            s8v v = *(const s8v*)(Vsrc + (size_t)dd * 2048 + kv0 + piece * 8);
            *(s8v*)(smem + 16384 + dd * 128 + ((piece * 16) ^ ((dd & 7) << 4))) = v;
        }
        __syncthreads();

        f4v s1[4] = {}; f4v s2[4] = {};
#pragma unroll
        for (int nt = 0; nt < 4; ++nt)
#pragma unroll
            for (int ks = 0; ks < 2; ++ks) {
                int ro = (nt * 16 + l15) * 128 + ((ks * 64 + g * 16) ^ swz);
                s1[nt] = __builtin_amdgcn_mfma_f32_16x16x32_bf16(q1[ks], *(const s8v*)(smem + ro), s1[nt], 0, 0, 0);
                s2[nt] = __builtin_amdgcn_mfma_f32_16x16x32_bf16(q2[ks], *(const s8v*)(smem + 8192 + ro), s2[nt], 0, 0, 0);
            }
#pragma unroll
        for (int nt = 0; nt < 4; ++nt)
#pragma unroll
            for (int r = 0; r < 4; ++r) {
                float p1 = __expf(s1[nt][r] * 0.125f - m1[r]) * il1[r];
                float p2 = __expf(s2[nt][r] * 0.125f - m2[r]) * il2[r];
                float v = p1 - lam * p2;
                awS[(wave * 16 + g * 4 + r) * 68 + nt * 16 + l15] = v;
                Pw[(g * 4 + r) * 72 + nt * 16 + l15] = (short)f2bf(v);
            }
        __syncthreads();

        // PV from LDS
#pragma unroll
        for (int ks = 0; ks < 2; ++ks) {
            s8v pf = *(const s8v*)(Pw + l15 * 72 + ks * 32 + g * 8);
#pragma unroll
            for (int dn = 0; dn < 8; ++dn) {
                int ro = 16384 + (dn * 16 + l15) * 128 + ((ks * 64 + g * 16) ^ swz);
                po[dn] = __builtin_amdgcn_mfma_f32_16x16x32_bf16(pf, *(const s8v*)(smem + ro), po[dn], 0, 0, 0);
            }
        }

        // coalesced aw dump (reads awS, all rows)
        {
            int row = t >> 2, c16 = (t & 3) * 16;
            const float* sp = awS + row * 68 + c16;
            float* dp = awb + (size_t)row * S + kv0 + c16;
#pragma unroll
            for (int j = 0; j < 4; ++j)
                *(float4*)(dp + j * 4) = *(const float4*)(sp + j * 4);
        }
    }

    // ---- epilogue: RMS-norm over 128, * subln_w * (1-lambda_init) ----
    float sw[8];
#pragma unroll
    for (int dn = 0; dn < 8; ++dn) sw[dn] = subw[dn * 16 + l15];
#pragma unroll
    for (int r = 0; r < 4; ++r) {
        float ss = 0.f;
#pragma unroll
        for (int dn = 0; dn < 8; ++dn) ss += po[dn][r] * po[dn][r];
#pragma unroll
        for (int off = 1; off < 16; off <<= 1) ss += __shfl_xor(ss, off);
        float rs = rsqrtf(ss * (1.0f / 128.0f) + 1e-5f) * OUT_SCALE;
        u16* dst = an + ((size_t)b * S + wrow0 + g * 4 + r) * D + h * 128;
#pragma unroll
        for (int dn = 0; dn < 8; ++dn)
            dst[dn * 16 + l15] = f2bf(po[dn][r] * rs * sw[dn]);
    }
}

extern "C" void kernel_launch(void* const* d_in, const int* in_sizes, int n_in,
                              void* d_out, int out_size, void* d_ws, size_t ws_size,
                              hipStream_t stream)
{
    const float* query = (const float*)d_in[0];
    const float* key   = (const float*)d_in[1];
    const float* value = (const float*)d_in[2];
    const float* wq_w  = (const float*)d_in[3];
    const float* wq_b  = (const float*)d_in[4];
    const float* wk_w  = (const float*)d_in[5];
    const float* wk_b  = (const float*)d_in[6];
    const float* wv_w  = (const float*)d_in[7];
    const float* wv_b  = (const float*)d_in[8];
    const float* fc_w  = (const float*)d_in[9];
    const float* fc_b  = (const float*)d_in[10];
    const float* lq1   = (const float*)d_in[11];
    const float* lk1   = (const float*)d_in[12];
    const float* lq2   = (const float*)d_in[13];
    const float* lk2   = (const float*)d_in[14];
    const float* subw  = (const float*)d_in[15];

    const size_t MB = 1024 * 1024;
    char* ws = (char*)d_ws;
    u16*   Qbf = (u16*)(ws);             // [2][2048][1024] bf16 proj out
    u16*   Kbf = (u16*)(ws + 8 * MB);
    u16*   Vtg = (u16*)(ws + 16 * MB);   // [2][1024][2048] bf16 (transposed)
    u16*   ANb = (u16*)(ws + 24 * MB);   // [4096][1024] bf16
    u16*   wqb = (u16*)(ws + 32 * MB);   // bf16 weights
    u16*   wkb = (u16*)(ws + 34 * MB);
    u16*   wvb = (u16*)(ws + 36 * MB);
    u16*   fcb = (u16*)(ws + 38 * MB);
    float* lamp = (float*)(ws + 40 * MB);

    float* out0 = (float*)d_out;
    float* awp  = out0 + (size_t)4096 * 1024;
    // converted bf16 inputs parked in the aw output region (rewritten by attn later)
    u16* qx = (u16*)awp;
    u16* kx = qx + (size_t)4096 * 1024;
    u16* vx = kx + (size_t)4096 * 1024;

    cvt_kernel<<<dim3(8192), dim3(256), 0, stream>>>(query, key, value, wq_w, wk_w, wv_w, fc_w,
                                                     qx, kx, vx, wqb, wkb, wvb, fcb);
    dim3 grid(32, 16), blk(256);
    gemm128<0><<<grid, blk, 0, stream>>>(qx, wqb, wq_b, Qbf);
    gemm128<0><<<grid, blk, 0, stream>>>(kx, wkb, wk_b, Kbf);
    gemm128<1><<<grid, blk, 0, stream>>>(vx, wvb, wv_b, Vtg);
    lam_kernel<<<dim3(1), dim3(64), 0, stream>>>(lq1, lk1, lq2, lk2, lamp);
    attn_kernel<<<dim3(512), blk, 0, stream>>>(Qbf, Kbf, Vtg, lamp, subw, awp, ANb);
    gemm128<2><<<grid, blk, 0, stream>>>(ANb, fcb, fc_b, out0);
}

// Round 5
// 277.499 us; speedup vs baseline: 2.4252x; 1.0431x over previous
//
#include <hip/hip_runtime.h>
#include <stdint.h>

#define DEV __device__ __forceinline__

typedef short s8v __attribute__((ext_vector_type(8)));      // 8 x bf16 (as i16 payload)
typedef float f4v __attribute__((ext_vector_type(4)));      // MFMA accumulator
typedef unsigned short u16;

static constexpr float LAMBDA_INIT = 0.783605766531624464f;
static constexpr float OUT_SCALE   = 0.216394233468375536f;  // 1 - LAMBDA_INIT

DEV u16 f2bf(float f) {
    uint32_t u = __builtin_bit_cast(uint32_t, f);
    u += 0x7fffu + ((u >> 16) & 1u);          // round-to-nearest-even
    return (u16)(u >> 16);
}
DEV float bf2f(u16 v) {
    return __builtin_bit_cast(float, (uint32_t)v << 16);
}

// ---------------- f32 -> bf16 bulk convert (7 tensors, one launch) --------
__global__ __launch_bounds__(256)
void cvt_kernel(const float* __restrict__ q, const float* __restrict__ k,
                const float* __restrict__ v, const float* __restrict__ w0,
                const float* __restrict__ w1, const float* __restrict__ w2,
                const float* __restrict__ w3,
                u16* qo, u16* ko, u16* vo, u16* o0, u16* o1, u16* o2, u16* o3)
{
    int bid = blockIdx.x;
    const float* src; u16* dst; int base;
    if      (bid < 2048) { src = q;  dst = qo; base = bid * 2048; }
    else if (bid < 4096) { src = k;  dst = ko; base = (bid - 2048) * 2048; }
    else if (bid < 6144) { src = v;  dst = vo; base = (bid - 4096) * 2048; }
    else if (bid < 6656) { src = w0; dst = o0; base = (bid - 6144) * 2048; }
    else if (bid < 7168) { src = w1; dst = o1; base = (bid - 6656) * 2048; }
    else if (bid < 7680) { src = w2; dst = o2; base = (bid - 7168) * 2048; }
    else                 { src = w3; dst = o3; base = (bid - 7680) * 2048; }
    int i = base + threadIdx.x * 8;
    float4 a = *(const float4*)(src + i);
    float4 b = *(const float4*)(src + i + 4);
    u16 r[8] = { f2bf(a.x), f2bf(a.y), f2bf(a.z), f2bf(a.w),
                 f2bf(b.x), f2bf(b.y), f2bf(b.z), f2bf(b.w) };
    *(s8v*)(dst + i) = *(const s8v*)r;
}

// ---------------- GEMM: C[M,N-tile] = A[M,K]bf16 @ W[N,K]bf16^T + bias -----
template<int OUT_MODE>
__global__ __launch_bounds__(256)
void gemm128(const u16* __restrict__ A, const u16* __restrict__ W,
             const float* __restrict__ bias, void* __restrict__ Cp)
{
    constexpr int K = 1024;
    __shared__ __align__(16) char smem[OUT_MODE == 2 ? 32768 : 24576];
    const int m0 = blockIdx.x * 128, n0 = blockIdx.y * 64;
    const int t = threadIdx.x, lane = t & 63, wave = t >> 6;
    const int l15 = lane & 15, g = lane >> 4;

    f4v acc[2][4] = {};

    for (int k0 = 0; k0 < K; k0 += 64) {
#pragma unroll
        for (int i = 0; i < 4; ++i) {            // A: 16KB
            int idx = t + i * 256, row = idx >> 3, piece = idx & 7;
            s8v v = *(const s8v*)(A + (size_t)(m0 + row) * K + k0 + piece * 8);
            *(s8v*)(smem + row * 128 + ((piece * 16) ^ ((row & 7) << 4))) = v;
        }
#pragma unroll
        for (int i = 0; i < 2; ++i) {            // B: 8KB
            int idx = t + i * 256, row = idx >> 3, piece = idx & 7;
            s8v v = *(const s8v*)(W + (size_t)(n0 + row) * K + k0 + piece * 8);
            *(s8v*)(smem + 16384 + row * 128 + ((piece * 16) ^ ((row & 7) << 4))) = v;
        }
        __syncthreads();
#pragma unroll
        for (int ks = 0; ks < 2; ++ks) {
            s8v af[2], bf4[4];
#pragma unroll
            for (int mt = 0; mt < 2; ++mt) {
                int row = wave * 32 + mt * 16 + l15;
                af[mt] = *(const s8v*)(smem + row * 128 + ((ks * 64 + g * 16) ^ ((l15 & 7) << 4)));
            }
#pragma unroll
            for (int nt = 0; nt < 4; ++nt) {
                int row = nt * 16 + l15;
                bf4[nt] = *(const s8v*)(smem + 16384 + row * 128 + ((ks * 64 + g * 16) ^ ((l15 & 7) << 4)));
            }
#pragma unroll
            for (int mt = 0; mt < 2; ++mt)
#pragma unroll
                for (int nt = 0; nt < 4; ++nt)
                    acc[mt][nt] = __builtin_amdgcn_mfma_f32_16x16x32_bf16(af[mt], bf4[nt], acc[mt][nt], 0, 0, 0);
        }
        __syncthreads();
    }

    float bv[4];
#pragma unroll
    for (int nt = 0; nt < 4; ++nt) bv[nt] = bias[n0 + nt * 16 + l15];

    if (OUT_MODE == 0) {
        u16* rep = (u16*)smem;                    // [128][64]
#pragma unroll
        for (int mt = 0; mt < 2; ++mt)
#pragma unroll
            for (int nt = 0; nt < 4; ++nt)
#pragma unroll
                for (int r = 0; r < 4; ++r)
                    rep[(wave * 32 + mt * 16 + g * 4 + r) * 64 + nt * 16 + l15] = f2bf(acc[mt][nt][r] + bv[nt]);
        __syncthreads();
        u16* C = (u16*)Cp;
#pragma unroll
        for (int j = 0; j < 4; ++j) {
            int m = j * 32 + (t >> 3), chunk = t & 7;
            s8v v = *(const s8v*)(smem + m * 128 + chunk * 16);
            *(s8v*)(C + (size_t)(m0 + m) * 1024 + n0 + chunk * 8) = v;
        }
    } else if (OUT_MODE == 1) {
        u16* LT = (u16*)smem;                     // [64 n][136]
#pragma unroll
        for (int mt = 0; mt < 2; ++mt)
#pragma unroll
            for (int nt = 0; nt < 4; ++nt)
#pragma unroll
                for (int r = 0; r < 4; ++r)
                    LT[(nt * 16 + l15) * 136 + wave * 32 + mt * 16 + g * 4 + r] = f2bf(acc[mt][nt][r] + bv[nt]);
        __syncthreads();
        u16* C = (u16*)Cp;
        const int b = m0 >> 11, s0 = m0 & 2047;
#pragma unroll
        for (int j = 0; j < 4; ++j) {
            int n = j * 16 + (t >> 4), chunk = t & 15;
            s8v v = *(const s8v*)(smem + n * 272 + chunk * 16);
            *(s8v*)(C + ((size_t)b * 1024 + n0 + n) * 2048 + s0 + chunk * 8) = v;
        }
    } else {
        float* rep = (float*)smem;                // [128][64] f32 = 32KB
#pragma unroll
        for (int mt = 0; mt < 2; ++mt)
#pragma unroll
            for (int nt = 0; nt < 4; ++nt)
#pragma unroll
                for (int r = 0; r < 4; ++r)
                    rep[(wave * 32 + mt * 16 + g * 4 + r) * 64 + nt * 16 + l15] = acc[mt][nt][r] + bv[nt];
        __syncthreads();
        float* C = (float*)Cp;
#pragma unroll
        for (int j = 0; j < 8; ++j) {
            int m = j * 16 + (t >> 4), c4 = t & 15;
            float4 v = *(const float4*)(smem + m * 256 + c4 * 16);
            *(float4*)(C + (size_t)(m0 + m) * 1024 + n0 + c4 * 4) = v;
        }
    }
}

// ---------------- lambda scalar --------------------------------------------
__global__ void lam_kernel(const float* lq1, const float* lk1,
                           const float* lq2, const float* lk2, float* out)
{
    int t = threadIdx.x;  // 64
    float p1 = lq1[t] * lk1[t], p2 = lq2[t] * lk2[t];
#pragma unroll
    for (int off = 1; off < 64; off <<= 1) {
        p1 += __shfl_xor(p1, off);
        p2 += __shfl_xor(p2, off);
    }
    if (t == 0) out[0] = expf(p1) - expf(p2) + LAMBDA_INIT;
}

// ---------------- differential attention -----------------------------------
// 512 blocks = b(2) x h(8) x qtile(32); 8 waves (512 thr).
// wave w: qw = w>>1 owns 16 q-rows; kw = w&1 owns the kw-th 32-col kv half.
__global__ __launch_bounds__(512, 4)
void attn_kernel(const u16* __restrict__ Qb, const u16* __restrict__ Kb,
                 const u16* __restrict__ Vt, const float* __restrict__ lamp,
                 const float* __restrict__ subw, float* __restrict__ aw,
                 u16* __restrict__ an)
{
    constexpr int S = 2048, D = 1024;
    __shared__ __align__(16) char smem[41984];
    // Ks @0: [2 sub][64 kv][128B] swizzled (16KB)
    // Vs @16384: [128 d][128B kv] swizzled (16KB)
    // P  @32768: [64][72] u16 (9216B); sst overlays P (pass-1 only)
    // Po @0: [64][128] f32 (32KB) overlays Ks+Vs (epilogue only)
    const int bid = blockIdx.x;
    const int qt = bid & 31, h = (bid >> 5) & 7, b = bid >> 8;
    const int t = threadIdx.x, lane = t & 63, w = t >> 6;
    const int qw = w >> 1, kw = w & 1;
    const int l15 = lane & 15, g = lane >> 4;
    const int qrow0 = qt * 64, wrow0 = qrow0 + qw * 16;
    const float lam = lamp[0];

    short* P   = (short*)(smem + 32768);
    float* sst = (float*)(smem + 32768);   // [8][4][16]
    float* Po  = (float*)smem;             // [64][128]

    const u16* Qbase = Qb + ((size_t)b * S + wrow0 + l15) * D + h * 128;
    s8v q1[2], q2[2];
#pragma unroll
    for (int ks = 0; ks < 2; ++ks) {
        q1[ks] = *(const s8v*)(Qbase + ks * 32 + g * 8);
        q2[ks] = *(const s8v*)(Qbase + 64 + ks * 32 + g * 8);
    }
    const u16* Ksrc = Kb + (size_t)b * S * D + h * 128;
    const u16* Vsrc = Vt + ((size_t)b * 1024 + h * 128) * 2048;
    const int swz = (l15 & 7) << 4;

    float m1[4], l1[4], m2[4], l2[4];
#pragma unroll
    for (int r = 0; r < 4; ++r) { m1[r] = -1e30f; l1[r] = 0.f; m2[r] = -1e30f; l2[r] = 0.f; }

    // ---- pass 1: per-(wave kv-half) softmax stats, K staged + reg-prefetch ----
    s8v kreg[2];
#pragma unroll
    for (int i = 0; i < 2; ++i) {
        int idx = t + i * 512, row = idx >> 4, piece = idx & 15;
        kreg[i] = *(const s8v*)(Ksrc + (size_t)row * D + piece * 8);
    }
    for (int kt = 0; kt < 32; ++kt) {
        __syncthreads();
#pragma unroll
        for (int i = 0; i < 2; ++i) {
            int idx = t + i * 512, row = idx >> 4, piece = idx & 15;
            int sub = piece >> 3, colB = (piece & 7) * 16;
            *(s8v*)(smem + sub * 8192 + row * 128 + (colB ^ ((row & 7) << 4))) = kreg[i];
        }
        __syncthreads();
        if (kt < 31) {
            const u16* src = Ksrc + (size_t)(kt + 1) * 64 * D;
#pragma unroll
            for (int i = 0; i < 2; ++i) {
                int idx = t + i * 512, row = idx >> 4, piece = idx & 15;
                kreg[i] = *(const s8v*)(src + (size_t)row * D + piece * 8);
            }
        }

        f4v s1[2] = {}; f4v s2[2] = {};
#pragma unroll
        for (int nt = 0; nt < 2; ++nt)
#pragma unroll
            for (int ks = 0; ks < 2; ++ks) {
                int ro = (kw * 32 + nt * 16 + l15) * 128 + ((ks * 64 + g * 16) ^ swz);
                s1[nt] = __builtin_amdgcn_mfma_f32_16x16x32_bf16(q1[ks], *(const s8v*)(smem + ro), s1[nt], 0, 0, 0);
                s2[nt] = __builtin_amdgcn_mfma_f32_16x16x32_bf16(q2[ks], *(const s8v*)(smem + 8192 + ro), s2[nt], 0, 0, 0);
            }
#pragma unroll
        for (int r = 0; r < 4; ++r) {
            float a0 = fmaxf(s1[0][r], s1[1][r]) * 0.125f;
            float a1 = fmaxf(s2[0][r], s2[1][r]) * 0.125f;
#pragma unroll
            for (int off = 1; off < 16; off <<= 1) {
                a0 = fmaxf(a0, __shfl_xor(a0, off));
                a1 = fmaxf(a1, __shfl_xor(a1, off));
            }
            float n1 = fmaxf(m1[r], a0), n2 = fmaxf(m2[r], a1);
            float t1 = __expf(s1[0][r] * 0.125f - n1) + __expf(s1[1][r] * 0.125f - n1);
            float t2 = __expf(s2[0][r] * 0.125f - n2) + __expf(s2[1][r] * 0.125f - n2);
#pragma unroll
            for (int off = 1; off < 16; off <<= 1) {
                t1 += __shfl_xor(t1, off);
                t2 += __shfl_xor(t2, off);
            }
            l1[r] = l1[r] * __expf(m1[r] - n1) + t1; m1[r] = n1;
            l2[r] = l2[r] * __expf(m2[r] - n2) + t2; m2[r] = n2;
        }
    }

    // ---- merge kv-half stats across kw pairs ----
    if (l15 == 0) {
#pragma unroll
        for (int r = 0; r < 4; ++r) {
            int row = g * 4 + r;
            sst[(w * 4 + 0) * 16 + row] = m1[r];
            sst[(w * 4 + 1) * 16 + row] = l1[r];
            sst[(w * 4 + 2) * 16 + row] = m2[r];
            sst[(w * 4 + 3) * 16 + row] = l2[r];
        }
    }
    __syncthreads();
    float il1[4], il2[4];
    {
        const int p = w ^ 1;
#pragma unroll
        for (int r = 0; r < 4; ++r) {
            int row = g * 4 + r;
            float ma = sst[(w * 4 + 0) * 16 + row], mb = sst[(p * 4 + 0) * 16 + row];
            float M1 = fmaxf(ma, mb);
            float L1 = sst[(w * 4 + 1) * 16 + row] * __expf(ma - M1)
                     + sst[(p * 4 + 1) * 16 + row] * __expf(mb - M1);
            float mc = sst[(w * 4 + 2) * 16 + row], md = sst[(p * 4 + 2) * 16 + row];
            float M2 = fmaxf(mc, md);
            float L2 = sst[(w * 4 + 3) * 16 + row] * __expf(mc - M2)
                     + sst[(p * 4 + 3) * 16 + row] * __expf(md - M2);
            m1[r] = M1; il1[r] = 1.f / L1;
            m2[r] = M2; il2[r] = 1.f / L2;
        }
    }

    f4v po[8] = {};   // partial PV over this wave's kv half
    float* awb = aw + ((size_t)(b * 8 + h) * S + qrow0) * S;

    // ---- pass 2: scores, aw (via P bf16), partial PV; K+V reg-prefetch ----
    s8v vreg[2];
#pragma unroll
    for (int i = 0; i < 2; ++i) {
        int idx = t + i * 512;
        { int row = idx >> 4, piece = idx & 15;
          kreg[i] = *(const s8v*)(Ksrc + (size_t)row * D + piece * 8); }
        { int dd = idx >> 3, piece = idx & 7;
          vreg[i] = *(const s8v*)(Vsrc + (size_t)dd * 2048 + piece * 8); }
    }
    for (int kt = 0; kt < 32; ++kt) {
        const int kv0 = kt * 64;
        __syncthreads();   // A: staging + P regions free
#pragma unroll
        for (int i = 0; i < 2; ++i) {
            int idx = t + i * 512;
            { int row = idx >> 4, piece = idx & 15;
              int sub = piece >> 3, colB = (piece & 7) * 16;
              *(s8v*)(smem + sub * 8192 + row * 128 + (colB ^ ((row & 7) << 4))) = kreg[i]; }
            { int dd = idx >> 3, piece = idx & 7;
              *(s8v*)(smem + 16384 + dd * 128 + ((piece * 16) ^ ((dd & 7) << 4))) = vreg[i]; }
        }
        __syncthreads();   // B: tiles ready
        if (kt < 31) {
            const u16* ksp = Ksrc + (size_t)(kv0 + 64) * D;
            const u16* vsp = Vsrc + kv0 + 64;
#pragma unroll
            for (int i = 0; i < 2; ++i) {
                int idx = t + i * 512;
                { int row = idx >> 4, piece = idx & 15;
                  kreg[i] = *(const s8v*)(ksp + (size_t)row * D + piece * 8); }
                { int dd = idx >> 3, piece = idx & 7;
                  vreg[i] = *(const s8v*)(vsp + (size_t)dd * 2048 + piece * 8); }
            }
        }

        f4v s1[2] = {}; f4v s2[2] = {};
#pragma unroll
        for (int nt = 0; nt < 2; ++nt)
#pragma unroll
            for (int ks = 0; ks < 2; ++ks) {
                int ro = (kw * 32 + nt * 16 + l15) * 128 + ((ks * 64 + g * 16) ^ swz);
                s1[nt] = __builtin_amdgcn_mfma_f32_16x16x32_bf16(q1[ks], *(const s8v*)(smem + ro), s1[nt], 0, 0, 0);
                s2[nt] = __builtin_amdgcn_mfma_f32_16x16x32_bf16(q2[ks], *(const s8v*)(smem + 8192 + ro), s2[nt], 0, 0, 0);
            }
#pragma unroll
        for (int nt = 0; nt < 2; ++nt)
#pragma unroll
            for (int r = 0; r < 4; ++r) {
                float p1 = __expf(s1[nt][r] * 0.125f - m1[r]) * il1[r];
                float p2 = __expf(s2[nt][r] * 0.125f - m2[r]) * il2[r];
                float v = p1 - lam * p2;
                P[(qw * 16 + g * 4 + r) * 72 + kw * 32 + nt * 16 + l15] = (short)f2bf(v);
            }
        __syncthreads();   // C: P ready

        // PV: one MFMA per dn over this wave's 32 kv cols
        s8v pf = *(const s8v*)(P + (qw * 16 + l15) * 72 + kw * 32 + g * 8);
#pragma unroll
        for (int dn = 0; dn < 8; ++dn) {
            int ro = 16384 + (dn * 16 + l15) * 128 + ((kw * 64 + g * 16) ^ swz);
            po[dn] = __builtin_amdgcn_mfma_f32_16x16x32_bf16(pf, *(const s8v*)(smem + ro), po[dn], 0, 0, 0);
        }

        // coalesced aw dump from P (bf16 -> f32 exact)
        {
            int row = t >> 3, c8 = (t & 7) * 8;
            s8v a = *(const s8v*)(P + row * 72 + c8);
            float4 o0 = { bf2f((u16)a[0]), bf2f((u16)a[1]), bf2f((u16)a[2]), bf2f((u16)a[3]) };
            float4 o1 = { bf2f((u16)a[4]), bf2f((u16)a[5]), bf2f((u16)a[6]), bf2f((u16)a[7]) };
            float* dp = awb + (size_t)row * S + kv0 + c8;
            *(float4*)dp = o0;
            *(float4*)(dp + 4) = o1;
        }
    }

    // ---- combine partial PV across kw pairs (Po overlays Ks+Vs) ----
    __syncthreads();
    if (kw == 0) {
#pragma unroll
        for (int dn = 0; dn < 8; ++dn)
#pragma unroll
            for (int r = 0; r < 4; ++r)
                Po[(qw * 16 + g * 4 + r) * 128 + dn * 16 + l15] = po[dn][r];
    }
    __syncthreads();
    if (kw == 1) {
#pragma unroll
        for (int dn = 0; dn < 8; ++dn)
#pragma unroll
            for (int r = 0; r < 4; ++r)
                Po[(qw * 16 + g * 4 + r) * 128 + dn * 16 + l15] += po[dn][r];
    }
    __syncthreads();

    // ---- epilogue: RMS-norm over 128, * subln_w * (1-lambda_init) ----
    {
        const int row = t >> 3, c0 = (t & 7) * 16;
        float ss = 0.f;
#pragma unroll
        for (int j = 0; j < 4; ++j) {
            float4 v4 = *(const float4*)(Po + row * 128 + c0 + j * 4);
            ss += v4.x * v4.x + v4.y * v4.y + v4.z * v4.z + v4.w * v4.w;
        }
#pragma unroll
        for (int off = 1; off < 8; off <<= 1) ss += __shfl_xor(ss, off);
        float rs = rsqrtf(ss * (1.0f / 128.0f) + 1e-5f) * OUT_SCALE;
        u16* dst = an + ((size_t)b * S + qrow0 + row) * D + h * 128;
#pragma unroll
        for (int j = 0; j < 2; ++j) {
            u16 tmp[8];
#pragma unroll
            for (int e = 0; e < 8; ++e) {
                int c = c0 + j * 8 + e;
                tmp[e] = f2bf(Po[row * 128 + c] * rs * subw[c]);
            }
            *(s8v*)(dst + c0 + j * 8) = *(const s8v*)tmp;
        }
    }
}

extern "C" void kernel_launch(void* const* d_in, const int* in_sizes, int n_in,
                              void* d_out, int out_size, void* d_ws, size_t ws_size,
                              hipStream_t stream)
{
    const float* query = (const float*)d_in[0];
    const float* key   = (const float*)d_in[1];
    const float* value = (const float*)d_in[2];
    const float* wq_w  = (const float*)d_in[3];
    const float* wq_b  = (const float*)d_in[4];
    const float* wk_w  = (const float*)d_in[5];
    const float* wk_b  = (const float*)d_in[6];
    const float* wv_w  = (const float*)d_in[7];
    const float* wv_b  = (const float*)d_in[8];
    const float* fc_w  = (const float*)d_in[9];
    const float* fc_b  = (const float*)d_in[10];
    const float* lq1   = (const float*)d_in[11];
    const float* lk1   = (const float*)d_in[12];
    const float* lq2   = (const float*)d_in[13];
    const float* lk2   = (const float*)d_in[14];
    const float* subw  = (const float*)d_in[15];

    const size_t MB = 1024 * 1024;
    char* ws = (char*)d_ws;
    u16*   Qbf = (u16*)(ws);             // [2][2048][1024] bf16 proj out
    u16*   Kbf = (u16*)(ws + 8 * MB);
    u16*   Vtg = (u16*)(ws + 16 * MB);   // [2][1024][2048] bf16 (transposed)
    u16*   ANb = (u16*)(ws + 24 * MB);   // [4096][1024] bf16
    u16*   wqb = (u16*)(ws + 32 * MB);   // bf16 weights
    u16*   wkb = (u16*)(ws + 34 * MB);
    u16*   wvb = (u16*)(ws + 36 * MB);
    u16*   fcb = (u16*)(ws + 38 * MB);
    float* lamp = (float*)(ws + 40 * MB);

    float* out0 = (float*)d_out;
    float* awp  = out0 + (size_t)4096 * 1024;
    // converted bf16 inputs parked in the aw output region (rewritten by attn later)
    u16* qx = (u16*)awp;
    u16* kx = qx + (size_t)4096 * 1024;
    u16* vx = kx + (size_t)4096 * 1024;

    cvt_kernel<<<dim3(8192), dim3(256), 0, stream>>>(query, key, value, wq_w, wk_w, wv_w, fc_w,
                                                     qx, kx, vx, wqb, wkb, wvb, fcb);
    dim3 grid(32, 16), blk(256);
    gemm128<0><<<grid, blk, 0, stream>>>(qx, wqb, wq_b, Qbf);
    gemm128<0><<<grid, blk, 0, stream>>>(kx, wkb, wk_b, Kbf);
    gemm128<1><<<grid, blk, 0, stream>>>(vx, wvb, wv_b, Vtg);
    lam_kernel<<<dim3(1), dim3(64), 0, stream>>>(lq1, lk1, lq2, lk2, lamp);
    attn_kernel<<<dim3(512), dim3(512), 0, stream>>>(Qbf, Kbf, Vtg, lamp, subw, awp, ANb);
    gemm128<2><<<grid, blk, 0, stream>>>(ANb, fcb, fc_b, out0);
}

// Round 6
// 194.713 us; speedup vs baseline: 3.4563x; 1.4252x over previous
//
#include <hip/hip_runtime.h>
#include <stdint.h>

#define DEV __device__ __forceinline__

typedef short s8v __attribute__((ext_vector_type(8)));      // 8 x bf16 (as i16 payload)
typedef float f4v __attribute__((ext_vector_type(4)));      // MFMA accumulator
typedef unsigned short u16;

static constexpr float LAMBDA_INIT = 0.783605766531624464f;
static constexpr float OUT_SCALE   = 0.216394233468375536f;  // 1 - LAMBDA_INIT

DEV u16 f2bf(float f) {
    uint32_t u = __builtin_bit_cast(uint32_t, f);
    u += 0x7fffu + ((u >> 16) & 1u);          // round-to-nearest-even
    return (u16)(u >> 16);
}
DEV float bf2f(u16 v) {
    return __builtin_bit_cast(float, (uint32_t)v << 16);
}

// ---------------- f32 -> bf16 bulk convert (7 tensors, one launch) --------
__global__ __launch_bounds__(256)
void cvt_kernel(const float* __restrict__ q, const float* __restrict__ k,
                const float* __restrict__ v, const float* __restrict__ w0,
                const float* __restrict__ w1, const float* __restrict__ w2,
                const float* __restrict__ w3,
                u16* qo, u16* ko, u16* vo, u16* o0, u16* o1, u16* o2, u16* o3)
{
    int bid = blockIdx.x;
    const float* src; u16* dst; int base;
    if      (bid < 2048) { src = q;  dst = qo; base = bid * 2048; }
    else if (bid < 4096) { src = k;  dst = ko; base = (bid - 2048) * 2048; }
    else if (bid < 6144) { src = v;  dst = vo; base = (bid - 4096) * 2048; }
    else if (bid < 6656) { src = w0; dst = o0; base = (bid - 6144) * 2048; }
    else if (bid < 7168) { src = w1; dst = o1; base = (bid - 6656) * 2048; }
    else if (bid < 7680) { src = w2; dst = o2; base = (bid - 7168) * 2048; }
    else                 { src = w3; dst = o3; base = (bid - 7680) * 2048; }
    int i = base + threadIdx.x * 8;
    float4 a = *(const float4*)(src + i);
    float4 b = *(const float4*)(src + i + 4);
    u16 r[8] = { f2bf(a.x), f2bf(a.y), f2bf(a.z), f2bf(a.w),
                 f2bf(b.x), f2bf(b.y), f2bf(b.z), f2bf(b.w) };
    *(s8v*)(dst + i) = *(const s8v*)r;
}

// ---------------- GEMM: C[M,N-tile] = A[M,K]bf16 @ W[N,K]bf16^T + bias -----
template<int OUT_MODE>
__global__ __launch_bounds__(256)
void gemm128(const u16* __restrict__ A, const u16* __restrict__ W,
             const float* __restrict__ bias, void* __restrict__ Cp)
{
    constexpr int K = 1024;
    __shared__ __align__(16) char smem[OUT_MODE == 2 ? 32768 : 24576];
    const int m0 = blockIdx.x * 128, n0 = blockIdx.y * 64;
    const int t = threadIdx.x, lane = t & 63, wave = t >> 6;
    const int l15 = lane & 15, g = lane >> 4;

    f4v acc[2][4] = {};

    for (int k0 = 0; k0 < K; k0 += 64) {
#pragma unroll
        for (int i = 0; i < 4; ++i) {            // A: 16KB
            int idx = t + i * 256, row = idx >> 3, piece = idx & 7;
            s8v v = *(const s8v*)(A + (size_t)(m0 + row) * K + k0 + piece * 8);
            *(s8v*)(smem + row * 128 + ((piece * 16) ^ ((row & 7) << 4))) = v;
        }
#pragma unroll
        for (int i = 0; i < 2; ++i) {            // B: 8KB
            int idx = t + i * 256, row = idx >> 3, piece = idx & 7;
            s8v v = *(const s8v*)(W + (size_t)(n0 + row) * K + k0 + piece * 8);
            *(s8v*)(smem + 16384 + row * 128 + ((piece * 16) ^ ((row & 7) << 4))) = v;
        }
        __syncthreads();
#pragma unroll
        for (int ks = 0; ks < 2; ++ks) {
            s8v af[2], bf4[4];
#pragma unroll
            for (int mt = 0; mt < 2; ++mt) {
                int row = wave * 32 + mt * 16 + l15;
                af[mt] = *(const s8v*)(smem + row * 128 + ((ks * 64 + g * 16) ^ ((l15 & 7) << 4)));
            }
#pragma unroll
            for (int nt = 0; nt < 4; ++nt) {
                int row = nt * 16 + l15;
                bf4[nt] = *(const s8v*)(smem + 16384 + row * 128 + ((ks * 64 + g * 16) ^ ((l15 & 7) << 4)));
            }
#pragma unroll
            for (int mt = 0; mt < 2; ++mt)
#pragma unroll
                for (int nt = 0; nt < 4; ++nt)
                    acc[mt][nt] = __builtin_amdgcn_mfma_f32_16x16x32_bf16(af[mt], bf4[nt], acc[mt][nt], 0, 0, 0);
        }
        __syncthreads();
    }

    float bv[4];
#pragma unroll
    for (int nt = 0; nt < 4; ++nt) bv[nt] = bias[n0 + nt * 16 + l15];

    if (OUT_MODE == 0) {
        u16* rep = (u16*)smem;                    // [128][64]
#pragma unroll
        for (int mt = 0; mt < 2; ++mt)
#pragma unroll
            for (int nt = 0; nt < 4; ++nt)
#pragma unroll
                for (int r = 0; r < 4; ++r)
                    rep[(wave * 32 + mt * 16 + g * 4 + r) * 64 + nt * 16 + l15] = f2bf(acc[mt][nt][r] + bv[nt]);
        __syncthreads();
        u16* C = (u16*)Cp;
#pragma unroll
        for (int j = 0; j < 4; ++j) {
            int m = j * 32 + (t >> 3), chunk = t & 7;
            s8v v = *(const s8v*)(smem + m * 128 + chunk * 16);
            *(s8v*)(C + (size_t)(m0 + m) * 1024 + n0 + chunk * 8) = v;
        }
    } else if (OUT_MODE == 1) {
        u16* LT = (u16*)smem;                     // [64 n][136]
#pragma unroll
        for (int mt = 0; mt < 2; ++mt)
#pragma unroll
            for (int nt = 0; nt < 4; ++nt)
#pragma unroll
                for (int r = 0; r < 4; ++r)
                    LT[(nt * 16 + l15) * 136 + wave * 32 + mt * 16 + g * 4 + r] = f2bf(acc[mt][nt][r] + bv[nt]);
        __syncthreads();
        u16* C = (u16*)Cp;
        const int b = m0 >> 11, s0 = m0 & 2047;
#pragma unroll
        for (int j = 0; j < 4; ++j) {
            int n = j * 16 + (t >> 4), chunk = t & 15;
            s8v v = *(const s8v*)(smem + n * 272 + chunk * 16);
            *(s8v*)(C + ((size_t)b * 1024 + n0 + n) * 2048 + s0 + chunk * 8) = v;
        }
    } else {
        float* rep = (float*)smem;                // [128][64] f32 = 32KB
#pragma unroll
        for (int mt = 0; mt < 2; ++mt)
#pragma unroll
            for (int nt = 0; nt < 4; ++nt)
#pragma unroll
                for (int r = 0; r < 4; ++r)
                    rep[(wave * 32 + mt * 16 + g * 4 + r) * 64 + nt * 16 + l15] = acc[mt][nt][r] + bv[nt];
        __syncthreads();
        float* C = (float*)Cp;
#pragma unroll
        for (int j = 0; j < 8; ++j) {
            int m = j * 16 + (t >> 4), c4 = t & 15;
            float4 v = *(const float4*)(smem + m * 256 + c4 * 16);
            *(float4*)(C + (size_t)(m0 + m) * 1024 + n0 + c4 * 4) = v;
        }
    }
}

// ---------------- differential attention -----------------------------------
// 512 blocks = b(2) x h(8) x qtile(32); 8 waves (512 thr).
// wave w: qw = w>>1 owns 16 q-rows; kw = w&1 owns the kw-th 32-col kv half.
// No-max softmax (scores ~N(0,1); f32 exp safe), deferred row-sum,
// double-buffered K/V (1 barrier/kt), wave-local P.
__global__ __launch_bounds__(512, 4)
void attn_kernel(const u16* __restrict__ Qb, const u16* __restrict__ Kb,
                 const u16* __restrict__ Vt,
                 const float* __restrict__ lq1, const float* __restrict__ lk1,
                 const float* __restrict__ lq2, const float* __restrict__ lk2,
                 const float* __restrict__ subw, float* __restrict__ aw,
                 u16* __restrict__ an)
{
    constexpr int S = 2048, D = 1024;
    __shared__ __align__(16) char smem[75776];
    // Kbuf0 @0 (16KB: [2 sub][64 kv][128B] swz) | Vbuf0 @16384 (16KB: [128 d][128B] swz)
    // Kbuf1 @32768 | Vbuf1 @49152 | P @65536 ([64][72] u16 = 9216B) | sst @74752 (1KB)
    // Po (epilogue) overlays @0 (32KB)
    const int bid0 = blockIdx.x;
    const int bid = (bid0 & 7) * 64 + (bid0 >> 3);   // XCD-chunked swizzle (512 = 8*64)
    const int qt = bid & 31, h = (bid >> 5) & 7, b = bid >> 8;
    const int t = threadIdx.x, lane = t & 63, w = t >> 6;
    const int qw = w >> 1, kw = w & 1;
    const int l15 = lane & 15, g = lane >> 4;
    const int qrow0 = qt * 64, wrow0 = qrow0 + qw * 16;

    short* P   = (short*)(smem + 65536);
    float* sst = (float*)(smem + 74752);   // [8 waves][2][16 rows]
    float* Po  = (float*)smem;             // [64][128] epilogue overlay

    // lambda (computed redundantly per block)
    float lam;
    {
        float p1 = lq1[lane] * lk1[lane], p2 = lq2[lane] * lk2[lane];
#pragma unroll
        for (int off = 1; off < 64; off <<= 1) {
            p1 += __shfl_xor(p1, off);
            p2 += __shfl_xor(p2, off);
        }
        lam = expf(p1) - expf(p2) + LAMBDA_INIT;
    }

    const u16* Qbase = Qb + ((size_t)b * S + wrow0 + l15) * D + h * 128;
    s8v q1[2], q2[2];
#pragma unroll
    for (int ks = 0; ks < 2; ++ks) {
        q1[ks] = *(const s8v*)(Qbase + ks * 32 + g * 8);
        q2[ks] = *(const s8v*)(Qbase + 64 + ks * 32 + g * 8);
    }
    const u16* Ksrc = Kb + (size_t)b * S * D + h * 128;
    const u16* Vsrc = Vt + ((size_t)b * 1024 + h * 128) * 2048;
    const int swz = (l15 & 7) << 4;

    // ---- pass 1: row-sums only (no max, deferred cross-lane reduce) ----
    float t1a[4] = {}, t2a[4] = {};
    s8v kreg[2], vreg[2];
    // prologue: kt0 -> Kbuf0; load kt1
#pragma unroll
    for (int i = 0; i < 2; ++i) {
        int idx = t + i * 512, row = idx >> 4, piece = idx & 15;
        kreg[i] = *(const s8v*)(Ksrc + (size_t)row * D + piece * 8);
    }
#pragma unroll
    for (int i = 0; i < 2; ++i) {
        int idx = t + i * 512, row = idx >> 4, piece = idx & 15;
        int sub = piece >> 3, colB = (piece & 7) * 16;
        *(s8v*)(smem + sub * 8192 + row * 128 + (colB ^ ((row & 7) << 4))) = kreg[i];
    }
#pragma unroll
    for (int i = 0; i < 2; ++i) {
        int idx = t + i * 512, row = idx >> 4, piece = idx & 15;
        kreg[i] = *(const s8v*)(Ksrc + (size_t)(64 + row) * D + piece * 8);
    }
    __syncthreads();

    for (int kt = 0; kt < 32; ++kt) {
        char* kcur = smem + (kt & 1) * 32768;
        char* knxt = smem + ((kt + 1) & 1) * 32768;
        if (kt < 31) {
#pragma unroll
            for (int i = 0; i < 2; ++i) {
                int idx = t + i * 512, row = idx >> 4, piece = idx & 15;
                int sub = piece >> 3, colB = (piece & 7) * 16;
                *(s8v*)(knxt + sub * 8192 + row * 128 + (colB ^ ((row & 7) << 4))) = kreg[i];
            }
        }
        if (kt < 30) {
            const u16* src = Ksrc + (size_t)(kt + 2) * 64 * D;
#pragma unroll
            for (int i = 0; i < 2; ++i) {
                int idx = t + i * 512, row = idx >> 4, piece = idx & 15;
                kreg[i] = *(const s8v*)(src + (size_t)row * D + piece * 8);
            }
        }
        f4v s1[2] = {}, s2[2] = {};
        __builtin_amdgcn_s_setprio(1);
#pragma unroll
        for (int nt = 0; nt < 2; ++nt)
#pragma unroll
            for (int ks = 0; ks < 2; ++ks) {
                int ro = (kw * 32 + nt * 16 + l15) * 128 + ((ks * 64 + g * 16) ^ swz);
                s1[nt] = __builtin_amdgcn_mfma_f32_16x16x32_bf16(q1[ks], *(const s8v*)(kcur + ro), s1[nt], 0, 0, 0);
                s2[nt] = __builtin_amdgcn_mfma_f32_16x16x32_bf16(q2[ks], *(const s8v*)(kcur + 8192 + ro), s2[nt], 0, 0, 0);
            }
        __builtin_amdgcn_s_setprio(0);
#pragma unroll
        for (int nt = 0; nt < 2; ++nt)
#pragma unroll
            for (int r = 0; r < 4; ++r) {
                t1a[r] += __expf(s1[nt][r] * 0.125f);
                t2a[r] += __expf(s2[nt][r] * 0.125f);
            }
        __syncthreads();
    }

    // one-time cross-lane reduce (l15 group) + kw-pair merge via sst
#pragma unroll
    for (int r = 0; r < 4; ++r) {
#pragma unroll
        for (int off = 1; off < 16; off <<= 1) {
            t1a[r] += __shfl_xor(t1a[r], off);
            t2a[r] += __shfl_xor(t2a[r], off);
        }
    }
    // prefetch pass2 kt0 (hide under stat exchange)
#pragma unroll
    for (int i = 0; i < 2; ++i) {
        int idx = t + i * 512;
        { int row = idx >> 4, piece = idx & 15;
          kreg[i] = *(const s8v*)(Ksrc + (size_t)row * D + piece * 8); }
        { int dd = idx >> 3, piece = idx & 7;
          vreg[i] = *(const s8v*)(Vsrc + (size_t)dd * 2048 + piece * 8); }
    }
    if (l15 == 0) {
#pragma unroll
        for (int r = 0; r < 4; ++r) {
            int row = g * 4 + r;
            sst[(w * 2 + 0) * 16 + row] = t1a[r];
            sst[(w * 2 + 1) * 16 + row] = t2a[r];
        }
    }
    // stage kt0 into buf0
#pragma unroll
    for (int i = 0; i < 2; ++i) {
        int idx = t + i * 512;
        { int row = idx >> 4, piece = idx & 15;
          int sub = piece >> 3, colB = (piece & 7) * 16;
          *(s8v*)(smem + sub * 8192 + row * 128 + (colB ^ ((row & 7) << 4))) = kreg[i]; }
        { int dd = idx >> 3, piece = idx & 7;
          *(s8v*)(smem + 16384 + dd * 128 + ((piece * 16) ^ ((dd & 7) << 4))) = vreg[i]; }
    }
    // load kt1
#pragma unroll
    for (int i = 0; i < 2; ++i) {
        int idx = t + i * 512;
        { int row = idx >> 4, piece = idx & 15;
          kreg[i] = *(const s8v*)(Ksrc + (size_t)(64 + row) * D + piece * 8); }
        { int dd = idx >> 3, piece = idx & 7;
          vreg[i] = *(const s8v*)(Vsrc + (size_t)dd * 2048 + 64 + piece * 8); }
    }
    __syncthreads();
    float il1[4], il2[4];
    {
        const int p = w ^ 1;
#pragma unroll
        for (int r = 0; r < 4; ++r) {
            int row = g * 4 + r;
            il1[r] = 1.f / (t1a[r] + sst[(p * 2 + 0) * 16 + row]);
            il2[r] = 1.f / (t2a[r] + sst[(p * 2 + 1) * 16 + row]);
        }
    }

    // ---- pass 2: scores, aw, partial PV; dbuf, 1 barrier/kt ----
    f4v po[8] = {};
    float* awb = aw + ((size_t)(b * 8 + h) * S + qrow0) * S;
    const int arow = lane >> 2, acol = kw * 32 + (lane & 3) * 8;

    for (int kt = 0; kt < 32; ++kt) {
        const int kv0 = kt * 64;
        char* cur = smem + (kt & 1) * 32768;
        char* nxt = smem + ((kt + 1) & 1) * 32768;
        if (kt < 31) {
#pragma unroll
            for (int i = 0; i < 2; ++i) {
                int idx = t + i * 512;
                { int row = idx >> 4, piece = idx & 15;
                  int sub = piece >> 3, colB = (piece & 7) * 16;
                  *(s8v*)(nxt + sub * 8192 + row * 128 + (colB ^ ((row & 7) << 4))) = kreg[i]; }
                { int dd = idx >> 3, piece = idx & 7;
                  *(s8v*)(nxt + 16384 + dd * 128 + ((piece * 16) ^ ((dd & 7) << 4))) = vreg[i]; }
            }
        }
        if (kt < 30) {
            const u16* ksp = Ksrc + (size_t)(kv0 + 128) * D;
            const u16* vsp = Vsrc + kv0 + 128;
#pragma unroll
            for (int i = 0; i < 2; ++i) {
                int idx = t + i * 512;
                { int row = idx >> 4, piece = idx & 15;
                  kreg[i] = *(const s8v*)(ksp + (size_t)row * D + piece * 8); }
                { int dd = idx >> 3, piece = idx & 7;
                  vreg[i] = *(const s8v*)(vsp + (size_t)dd * 2048 + piece * 8); }
            }
        }

        f4v s1[2] = {}, s2[2] = {};
        __builtin_amdgcn_s_setprio(1);
#pragma unroll
        for (int nt = 0; nt < 2; ++nt)
#pragma unroll
            for (int ks = 0; ks < 2; ++ks) {
                int ro = (kw * 32 + nt * 16 + l15) * 128 + ((ks * 64 + g * 16) ^ swz);
                s1[nt] = __builtin_amdgcn_mfma_f32_16x16x32_bf16(q1[ks], *(const s8v*)(cur + ro), s1[nt], 0, 0, 0);
                s2[nt] = __builtin_amdgcn_mfma_f32_16x16x32_bf16(q2[ks], *(const s8v*)(cur + 8192 + ro), s2[nt], 0, 0, 0);
            }
        __builtin_amdgcn_s_setprio(0);
#pragma unroll
        for (int nt = 0; nt < 2; ++nt)
#pragma unroll
            for (int r = 0; r < 4; ++r) {
                float p1 = __expf(s1[nt][r] * 0.125f) * il1[r];
                float p2 = __expf(s2[nt][r] * 0.125f) * il2[r];
                P[(qw * 16 + g * 4 + r) * 72 + kw * 32 + nt * 16 + l15] = (short)f2bf(p1 - lam * p2);
            }
        // wave-local P: in-order DS pipe orders write->read within the wave
        s8v pf = *(const s8v*)(P + (qw * 16 + l15) * 72 + kw * 32 + g * 8);
        __builtin_amdgcn_s_setprio(1);
#pragma unroll
        for (int dn = 0; dn < 8; ++dn) {
            const s8v* vf = (const s8v*)(cur + 16384 + (dn * 16 + l15) * 128 + ((kw * 64 + g * 16) ^ swz));
            po[dn] = __builtin_amdgcn_mfma_f32_16x16x32_bf16(pf, *vf, po[dn], 0, 0, 0);
        }
        __builtin_amdgcn_s_setprio(0);
        // aw dump (wave-local rows/cols, bf16->f32 exact)
        {
            s8v a = *(const s8v*)(P + (qw * 16 + arow) * 72 + acol);
            float4 o0 = { bf2f((u16)a[0]), bf2f((u16)a[1]), bf2f((u16)a[2]), bf2f((u16)a[3]) };
            float4 o1 = { bf2f((u16)a[4]), bf2f((u16)a[5]), bf2f((u16)a[6]), bf2f((u16)a[7]) };
            float* dp = awb + (size_t)(qw * 16 + arow) * S + kv0 + acol;
            *(float4*)dp = o0;
            *(float4*)(dp + 4) = o1;
        }
        __syncthreads();
    }

    // ---- combine partial PV across kw pairs (Po overlays buf0) ----
    if (kw == 0) {
#pragma unroll
        for (int dn = 0; dn < 8; ++dn)
#pragma unroll
            for (int r = 0; r < 4; ++r)
                Po[(qw * 16 + g * 4 + r) * 128 + dn * 16 + l15] = po[dn][r];
    }
    __syncthreads();
    if (kw == 1) {
#pragma unroll
        for (int dn = 0; dn < 8; ++dn)
#pragma unroll
            for (int r = 0; r < 4; ++r)
                Po[(qw * 16 + g * 4 + r) * 128 + dn * 16 + l15] += po[dn][r];
    }
    __syncthreads();

    // ---- epilogue: RMS-norm over 128, * subln_w * (1-lambda_init) ----
    {
        const int row = t >> 3, c0 = (t & 7) * 16;
        float ss = 0.f;
#pragma unroll
        for (int j = 0; j < 4; ++j) {
            float4 v4 = *(const float4*)(Po + row * 128 + c0 + j * 4);
            ss += v4.x * v4.x + v4.y * v4.y + v4.z * v4.z + v4.w * v4.w;
        }
#pragma unroll
        for (int off = 1; off < 8; off <<= 1) ss += __shfl_xor(ss, off);
        float rs = rsqrtf(ss * (1.0f / 128.0f) + 1e-5f) * OUT_SCALE;
        u16* dst = an + ((size_t)b * S + qrow0 + row) * D + h * 128;
#pragma unroll
        for (int j = 0; j < 2; ++j) {
            u16 tmp[8];
#pragma unroll
            for (int e = 0; e < 8; ++e) {
                int c = c0 + j * 8 + e;
                tmp[e] = f2bf(Po[row * 128 + c] * rs * subw[c]);
            }
            *(s8v*)(dst + c0 + j * 8) = *(const s8v*)tmp;
        }
    }
}

extern "C" void kernel_launch(void* const* d_in, const int* in_sizes, int n_in,
                              void* d_out, int out_size, void* d_ws, size_t ws_size,
                              hipStream_t stream)
{
    const float* query = (const float*)d_in[0];
    const float* key   = (const float*)d_in[1];
    const float* value = (const float*)d_in[2];
    const float* wq_w  = (const float*)d_in[3];
    const float* wq_b  = (const float*)d_in[4];
    const float* wk_w  = (const float*)d_in[5];
    const float* wk_b  = (const float*)d_in[6];
    const float* wv_w  = (const float*)d_in[7];
    const float* wv_b  = (const float*)d_in[8];
    const float* fc_w  = (const float*)d_in[9];
    const float* fc_b  = (const float*)d_in[10];
    const float* lq1   = (const float*)d_in[11];
    const float* lk1   = (const float*)d_in[12];
    const float* lq2   = (const float*)d_in[13];
    const float* lk2   = (const float*)d_in[14];
    const float* subw  = (const float*)d_in[15];

    const size_t MB = 1024 * 1024;
    char* ws = (char*)d_ws;
    u16*   Qbf = (u16*)(ws);             // [2][2048][1024] bf16 proj out
    u16*   Kbf = (u16*)(ws + 8 * MB);
    u16*   Vtg = (u16*)(ws + 16 * MB);   // [2][1024][2048] bf16 (transposed)
    u16*   ANb = (u16*)(ws + 24 * MB);   // [4096][1024] bf16
    u16*   wqb = (u16*)(ws + 32 * MB);   // bf16 weights
    u16*   wkb = (u16*)(ws + 34 * MB);
    u16*   wvb = (u16*)(ws + 36 * MB);
    u16*   fcb = (u16*)(ws + 38 * MB);

    float* out0 = (float*)d_out;
    float* awp  = out0 + (size_t)4096 * 1024;
    // converted bf16 inputs parked in the aw output region (rewritten by attn later)
    u16* qx = (u16*)awp;
    u16* kx = qx + (size_t)4096 * 1024;
    u16* vx = kx + (size_t)4096 * 1024;

    cvt_kernel<<<dim3(8192), dim3(256), 0, stream>>>(query, key, value, wq_w, wk_w, wv_w, fc_w,
                                                     qx, kx, vx, wqb, wkb, wvb, fcb);
    dim3 grid(32, 16), blk(256);
    gemm128<0><<<grid, blk, 0, stream>>>(qx, wqb, wq_b, Qbf);
    gemm128<0><<<grid, blk, 0, stream>>>(kx, wkb, wk_b, Kbf);
    gemm128<1><<<grid, blk, 0, stream>>>(vx, wvb, wv_b, Vtg);
    attn_kernel<<<dim3(512), dim3(512), 0, stream>>>(Qbf, Kbf, Vtg, lq1, lk1, lq2, lk2,
                                                     subw, awp, ANb);
    gemm128<2><<<grid, blk, 0, stream>>>(ANb, fcb, fc_b, out0);
}